// Round 9
// baseline (1271.165 us; speedup 1.0000x reference)
//
#include <hip/hip_runtime.h>
#include <hip/hip_bf16.h>

// Problem constants (from reference)
#define NNODE 25000
#define PEDGE 400000
#define FDIM  224      // F = TF = 224; q/k: 7 heads x 32, v: 4 heads x 56
#define NORD  15
#define NXOUT (NNODE*FDIM)
#define NTILE2 6250    // PEDGE/64 (64-edge block tiles)

typedef __bf16 bf16x8 __attribute__((ext_vector_type(8)));
typedef short  s16x8  __attribute__((ext_vector_type(8)));
typedef float  f32x4  __attribute__((ext_vector_type(4)));

// MFMA wrapper: tolerate either v8bf16 or v8i16 builtin signature across ROCm versions.
template <typename V>
__device__ __forceinline__ auto mfma_impl(V a, V b, f32x4 c, int)
    -> decltype(__builtin_amdgcn_mfma_f32_16x16x32_bf16(a, b, c, 0, 0, 0)) {
  return __builtin_amdgcn_mfma_f32_16x16x32_bf16(a, b, c, 0, 0, 0);
}
template <typename V>
__device__ __forceinline__ f32x4 mfma_impl(V a, V b, f32x4 c, long) {
  return __builtin_amdgcn_mfma_f32_16x16x32_bf16(
      __builtin_bit_cast(s16x8, a), __builtin_bit_cast(s16x8, b), c, 0, 0, 0);
}
__device__ __forceinline__ f32x4 MFMA_BF16(bf16x8 a, bf16x8 b, f32x4 c) {
  return mfma_impl(a, b, c, 0);
}

__device__ __forceinline__ float siluf(float x) { return x / (1.0f + __expf(-x)); }
__device__ __forceinline__ unsigned short f2bf(float x) {
  __hip_bfloat16 h = __float2bfloat16(x);
  return __builtin_bit_cast(unsigned short, h);
}
__device__ __forceinline__ float bf2f(unsigned short u) {
  unsigned int v = ((unsigned int)u) << 16;
  return __builtin_bit_cast(float, v);
}

// DPP 16-lane row sum on the VALU pipe.
template <int CTRL>
__device__ __forceinline__ float dpp_radd(float v) {
  int s = __builtin_amdgcn_update_dpp(0, __builtin_bit_cast(int, v), CTRL, 0xf, 0xf, true);
  return v + __builtin_bit_cast(float, s);
}
__device__ __forceinline__ float row16_sum(float v) {
  v = dpp_radd<0xB1>(v);    // quad_perm [1,0,3,2]  (xor 1)
  v = dpp_radd<0x4E>(v);    // quad_perm [2,3,0,1]  (xor 2)
  v = dpp_radd<0x124>(v);   // row_ror:4
  v = dpp_radd<0x128>(v);   // row_ror:8
  return v;                 // all 16 lanes of the row hold the sum
}

// ---------------------------------------------------------------------------
// k_pre: (a) node q,k,v projections, 8 nodes/block, weights in registers;
//        (b) CSR row_start from sorted idx_i;
//        (c) W1cat (64x224 block-diag + bias row 35) -> swizzled bf16 (global)
//        (d) W2cat (224x224) -> swizzled bf16 (global)
// ---------------------------------------------------------------------------
#define NPB 8
#define NBNODE 3125   // 25000/8
__global__ __launch_bounds__(256) void k_pre(
    const float* __restrict__ x, const float* __restrict__ Wq,
    const float* __restrict__ Wk, const float* __restrict__ Wv,
    const int* __restrict__ idx_i,
    const float* __restrict__ W1r, const float* __restrict__ W1s,
    const float* __restrict__ b1r, const float* __restrict__ b1s,
    const float* __restrict__ W2r, const float* __restrict__ W2s,
    unsigned short* __restrict__ q_ws, unsigned short* __restrict__ k_ws,
    unsigned short* __restrict__ v_ws, int* __restrict__ rs,
    unsigned short* __restrict__ W1sw, unsigned short* __restrict__ W2sw) {
  int b = blockIdx.x, t = threadIdx.x;
  if (b < NBNODE) {
    __shared__ float xs[NPB * FDIM];           // 7,168 B
    int n0 = b * NPB;
    const float4* x4 = (const float4*)(x + n0 * FDIM);
    float4* xs4 = (float4*)xs;
    for (int i = t; i < NPB * (FDIM/4); i += 256) xs4[i] = x4[i];
    float wq[32], wk[32], wv[56];
    int h = 0, d = 0;
    if (t < FDIM) {
      #pragma unroll
      for (int j = 0; j < 32; j++) { wq[j] = Wq[t*32 + j]; wk[j] = Wk[t*32 + j]; }
      h = t / 56; d = t - h*56;
      #pragma unroll
      for (int j = 0; j < 56; j++) wv[j] = Wv[(h*56 + d)*56 + j];
    }
    __syncthreads();
    if (t < FDIM) {
      int qh = t >> 5;
      #pragma unroll
      for (int m = 0; m < NPB; m++) {
        const float* xr = xs + m*FDIM;
        const float* xh = xr + (qh << 5);
        float aq = 0.f, ak = 0.f;
        #pragma unroll
        for (int j = 0; j < 32; j++) { aq += wq[j]*xh[j]; ak += wk[j]*xh[j]; }
        int n = n0 + m;
        q_ws[n*FDIM + t] = f2bf(siluf(aq));
        k_ws[n*FDIM + t] = f2bf(siluf(ak));
        const float* xv = xr + h*56;
        float av = 0.f;
        #pragma unroll
        for (int j = 0; j < 56; j++) av += wv[j]*xv[j];
        v_ws[n*FDIM + t] = f2bf(av);   // no silu on v
      }
    }
  } else if (b < NBNODE + 1563) {
    int p = (b - NBNODE)*256 + t;
    if (p < PEDGE) {
      int cur = idx_i[p];
      if (p == 0) { for (int v = 0; v <= cur; v++) rs[v] = 0; }
      else { int prev = idx_i[p-1]; for (int v = prev+1; v <= cur; v++) rs[v] = p; }
      if (p == PEDGE-1) { for (int v = cur+1; v <= NNODE; v++) rs[v] = PEDGE; }
    }
  } else if (b == NBNODE + 1563) {
    // W1cat[row<64][col<224]; row 35 = b1cat (bias folded into GEMM)
    for (int lin = t; lin < 64*224; lin += 256) {
      int row = lin / 224, col = lin - row*224;
      float v = 0.f;
      if (row < 32) { if (col < 112) v = W1r[row*112 + col]; }
      else if (row < 35) { if (col >= 112) v = W1s[(row-32)*112 + (col-112)]; }
      else if (row == 35) v = (col < 112) ? b1r[col] : b1s[col-112];
      int nt = col >> 4, lanelo = col & 15, k = row >> 5, hi = (row >> 3) & 3, j = row & 7;
      W1sw[(((nt*2 + k)*64) + hi*16 + lanelo)*8 + j] = f2bf(v);
    }
  } else {
    // W2cat (224x224) -> swizzled global, output-linear (coalesced writes)
    int half = b - (NBNODE + 1564);      // 0 or 1
    int o0 = half * 25088;
    for (int o = o0 + t; o < o0 + 25088; o += 256) {
      int j = o & 7, lane = (o >> 3) & 63, rest = o >> 9;
      int hi = lane >> 4, lanelo = lane & 15;
      int k32 = rest % 7, nt = rest / 7;
      int row = k32*32 + hi*8 + j, col = nt*16 + lanelo;
      float v = (row < 112) ? W2r[row*224 + col] : W2s[(row-112)*224 + col];
      W2sw[o] = f2bf(v);
    }
  }
}

// ---------------------------------------------------------------------------
// k_edge R12: kt-outer layer-2 with AGPR-resident w accumulators.
//
// History: h-outer epilogues need aa[2][7]=56 persistent VGPRs -> spill
// ~300 MB at the (256,4) budget (R9, 219us best); K-split (R11) and
// mg-split (R10) both regressed. Inversion: kt OUTER, (h,t2) inner.
//   - A-fragment read from LDS ONCE per kt, feeds 8 independent MFMA
//     chains (ILP from chains, not from mg pairing). aa never persists.
//   - Persistent state = the w accumulators themselves, in AGPRs where
//     MFMA wants them (groups of 4h/3h -> max 32 regs).
//   - Consumer reads acc directly in C-layout (row=edge quad*4+r,
//     col=nt*16+mrow): scalar q/k gathers, 16 lanes read 32 contiguous
//     bytes of one q-row -> HW-coalesced. No wbuf, no f32 LDS reuse,
//     no TBAA fences; h1 stays bf16-live all of layer-2.
//   - 16 edges/wave (64/block, NTILE2=6250): LDS = 64x232x2 = 29,696 B
//     -> (256,4): 4 blocks/CU, 50% occ, 128-reg budget >> ~90 live.
//   - layer-1 keeps R11's verified block-diag halving: nt 0..6 u0-only
//     + scalar b1r; nt 7..13 u1-only (b1s via bias row u1[3]=1).
// Same-wave in-order LDS pipe orders layer-1 writes -> kt reads (proven
// R6/R9); no barriers.
// ---------------------------------------------------------------------------
#define HS2 232
__global__ __launch_bounds__(256, 4) void k_edge(
    const float* __restrict__ rbf, const float* __restrict__ cut,
    const float* __restrict__ ev,
    const int* __restrict__ idx_i, const int* __restrict__ idx_j,
    const unsigned short* __restrict__ W1sw,
    const unsigned short* __restrict__ W2sw,
    const float* __restrict__ b1r,
    const float* __restrict__ b2r, const float* __restrict__ b2s,
    const unsigned short* __restrict__ q_ws, const unsigned short* __restrict__ k_ws,
    float* __restrict__ alpha_ws) {
  __shared__ __bf16 h1s[64*HS2];    // 4 waves x 16 rows x 232 = 29,696 B
  int tid = threadIdx.x;
  int wave = tid >> 6, lane = tid & 63;
  int mrow = lane & 15, quad = lane >> 4;
  __bf16* h1w = h1s + wave*16*HS2;  // wave-private 16-row slice
  for (int T = blockIdx.x; T < NTILE2; T += gridDim.x) {
    int gbase = T*64 + wave*16;
    // ---- u fragments (single 16-edge group) ----
    bf16x8 u0, u1;
    {
      int e = gbase + mrow;
      float cu = cut[e];
      const float4* r4 = (const float4*)(rbf + e*32 + quad*8);
      float4 v0 = r4[0], v1 = r4[1];
      u0[0] = (__bf16)(v0.x*cu); u0[1] = (__bf16)(v0.y*cu);
      u0[2] = (__bf16)(v0.z*cu); u0[3] = (__bf16)(v0.w*cu);
      u0[4] = (__bf16)(v1.x*cu); u0[5] = (__bf16)(v1.y*cu);
      u0[6] = (__bf16)(v1.z*cu); u0[7] = (__bf16)(v1.w*cu);
      #pragma unroll
      for (int j = 0; j < 8; j++) u1[j] = (__bf16)0.f;
      if (quad == 0) {   // k = 32..35: l0 contraction + bias row (k=35)
        int ie = idx_i[e], je = idx_j[e];
        const float* evi = ev + ie*NORD; const float* evj = ev + je*NORD;
        float s0 = 0.f, s1 = 0.f, s2 = 0.f;
        #pragma unroll
        for (int o = 0; o < 3; o++)  { float dd = evj[o]-evi[o]; s0 += dd*dd; }
        #pragma unroll
        for (int o = 3; o < 8; o++)  { float dd = evj[o]-evi[o]; s1 += dd*dd; }
        #pragma unroll
        for (int o = 8; o < 15; o++) { float dd = evj[o]-evi[o]; s2 += dd*dd; }
        u1[0] = (__bf16)s0; u1[1] = (__bf16)s1; u1[2] = (__bf16)s2;
        u1[3] = (__bf16)1.0f;   // bias row k=35
      }
    }
    // ---- layer 1 (block-diag halved): nt 0..6 u0-only + scalar b1r ----
    #pragma unroll
    for (int nt = 0; nt < 7; nt++) {
      bf16x8 b0 = *(const bf16x8*)(W1sw + ((nt*2 + 0)*64 + lane)*8);
      float bv1 = b1r[nt*16 + mrow];
      f32x4 acc = {bv1, bv1, bv1, bv1};
      acc = MFMA_BF16(u0, b0, acc);
      #pragma unroll
      for (int r = 0; r < 4; r++)
        h1w[(quad*4 + r)*HS2 + nt*16 + mrow] = (__bf16)siluf(acc[r]);
    }
    // ---- layer 1: nt 7..13 u1-only (b1s via bias row) ----
    #pragma unroll
    for (int nt = 7; nt < 14; nt++) {
      bf16x8 b1 = *(const bf16x8*)(W1sw + ((nt*2 + 1)*64 + lane)*8);
      f32x4 acc = {0.f, 0.f, 0.f, 0.f};
      acc = MFMA_BF16(u1, b1, acc);
      #pragma unroll
      for (int r = 0; r < 4; r++)
        h1w[(quad*4 + r)*HS2 + nt*16 + mrow] = (__bf16)siluf(acc[r]);
    }
    // ---- owned-edge metadata (C-layout rows = quad*4+r) ----
    int ii[4], jj[4]; float cc[4];
    #pragma unroll
    for (int r = 0; r < 4; r++) {
      int ee = gbase + quad*4 + r;
      ii[r] = idx_i[ee]; jj[r] = idx_j[ee]; cc[r] = cut[ee];
    }
    // ======== group 1: h = 0..3 (acc 32 regs) ========
    {
      f32x4 acc[4][2];
      #pragma unroll
      for (int h = 0; h < 4; h++)
        #pragma unroll
        for (int t2 = 0; t2 < 2; t2++) {
          int colg = (h*2 + t2)*16 + mrow;
          float bv = b2r[colg] + b2s[colg];
          acc[h][t2] = f32x4{bv, bv, bv, bv};
        }
      #pragma unroll
      for (int kt = 0; kt < 7; kt++) {
        bf16x8 a = *(const bf16x8*)&h1w[mrow*HS2 + kt*32 + quad*8];
        #pragma unroll
        for (int h = 0; h < 4; h++)
          #pragma unroll
          for (int t2 = 0; t2 < 2; t2++) {
            int nt = h*2 + t2;
            bf16x8 bb = *(const bf16x8*)(W2sw + ((nt*7 + kt)*64 + lane)*8);
            acc[h][t2] = MFMA_BF16(a, bb, acc[h][t2]);
          }
      }
      // consumer (static unroll; acc consumed in C-layout)
      #pragma unroll
      for (int h = 0; h < 4; h++)
        #pragma unroll
        for (int r = 0; r < 4; r++) {
          float part = 0.f;
          #pragma unroll
          for (int t2 = 0; t2 < 2; t2++) {
            int colg = (h*2 + t2)*16 + mrow;
            part += acc[h][t2][r] * bf2f(q_ws[ii[r]*FDIM + colg])
                                  * bf2f(k_ws[jj[r]*FDIM + colg]);
          }
          float v = row16_sum(part);
          if (mrow == 0) alpha_ws[(gbase + quad*4 + r)*7 + h] = v * cc[r];
        }
    }
    // ======== group 2: h = 4..6 (acc 24 regs) ========
    {
      f32x4 acc[3][2];
      #pragma unroll
      for (int h = 0; h < 3; h++)
        #pragma unroll
        for (int t2 = 0; t2 < 2; t2++) {
          int colg = ((h + 4)*2 + t2)*16 + mrow;
          float bv = b2r[colg] + b2s[colg];
          acc[h][t2] = f32x4{bv, bv, bv, bv};
        }
      #pragma unroll
      for (int kt = 0; kt < 7; kt++) {
        bf16x8 a = *(const bf16x8*)&h1w[mrow*HS2 + kt*32 + quad*8];
        #pragma unroll
        for (int h = 0; h < 3; h++)
          #pragma unroll
          for (int t2 = 0; t2 < 2; t2++) {
            int nt = (h + 4)*2 + t2;
            bf16x8 bb = *(const bf16x8*)(W2sw + ((nt*7 + kt)*64 + lane)*8);
            acc[h][t2] = MFMA_BF16(a, bb, acc[h][t2]);
          }
      }
      #pragma unroll
      for (int h = 0; h < 3; h++)
        #pragma unroll
        for (int r = 0; r < 4; r++) {
          float part = 0.f;
          #pragma unroll
          for (int t2 = 0; t2 < 2; t2++) {
            int colg = ((h + 4)*2 + t2)*16 + mrow;
            part += acc[h][t2][r] * bf2f(q_ws[ii[r]*FDIM + colg])
                                  * bf2f(k_ws[jj[r]*FDIM + colg]);
          }
          float v = row16_sum(part);
          if (mrow == 0) alpha_ws[(gbase + quad*4 + r)*7 + h + 4] = v * cc[r];
        }
    }
  }
}

// ---------------------------------------------------------------------------
// k_agg: one wave per node; 4-wide v loads; unrolled x2; zeros for empty segs.
// ---------------------------------------------------------------------------
__global__ __launch_bounds__(256) void k_agg(
    const float* __restrict__ alpha_ws, const unsigned short* __restrict__ v_ws,
    const float* __restrict__ ylm, const int* __restrict__ idx_j,
    const int* __restrict__ rs, float* __restrict__ out) {
  int n = blockIdx.x*4 + (threadIdx.x >> 6);
  if (n >= NNODE) return;
  int lane = threadIdx.x & 63;
  int s = rs[n], e = rs[n+1];
  if (lane < 56) {
    int c = lane*4, h = lane/14;      // 4 cols per lane, same head (56%4==0)
    float ax = 0.f, ay = 0.f, az = 0.f, aw = 0.f;
    int p = s;
    for (; p + 1 < e; p += 2) {
      int j0 = idx_j[p], j1 = idx_j[p+1];
      float a0 = alpha_ws[p*7 + h], a1 = alpha_ws[(p+1)*7 + h];
      ushort4 w0 = *(const ushort4*)(v_ws + j0*FDIM + c);
      ushort4 w1 = *(const ushort4*)(v_ws + j1*FDIM + c);
      ax += a0*bf2f(w0.x) + a1*bf2f(w1.x);
      ay += a0*bf2f(w0.y) + a1*bf2f(w1.y);
      az += a0*bf2f(w0.z) + a1*bf2f(w1.z);
      aw += a0*bf2f(w0.w) + a1*bf2f(w1.w);
    }
    if (p < e) {
      int j0 = idx_j[p];
      float a0 = alpha_ws[p*7 + h];
      ushort4 w0 = *(const ushort4*)(v_ws + j0*FDIM + c);
      ax += a0*bf2f(w0.x); ay += a0*bf2f(w0.y);
      az += a0*bf2f(w0.z); aw += a0*bf2f(w0.w);
    }
    float4 o4 = {ax, ay, az, aw};
    *(float4*)(out + n*FDIM + c) = o4;
  } else {
    int o = lane - 56;                // 0..7 ; second col o+8 (8..14)
    int dg0 = (o < 3) ? 0 : ((o < 8) ? 1 : 2);
    float a0 = 0.f, a1 = 0.f;
    for (int p = s; p < e; p++) {
      const float* ap = alpha_ws + p*7 + 4;
      a0 += ap[dg0] * ylm[p*NORD + o];
      if (o < 7) a1 += ap[2] * ylm[p*NORD + o + 8];
    }
    out[NXOUT + n*NORD + o] = a0;
    if (o < 7) out[NXOUT + n*NORD + o + 8] = a1;
  }
}

extern "C" void kernel_launch(void* const* d_in, const int* in_sizes, int n_in,
                              void* d_out, int out_size, void* d_ws, size_t ws_size,
                              hipStream_t stream) {
  const float* x     = (const float*)d_in[0];
  const float* ev    = (const float*)d_in[1];
  const float* rbf   = (const float*)d_in[2];
  const float* ylm   = (const float*)d_in[3];
  const float* cut   = (const float*)d_in[4];
  const int*   idx_i = (const int*)d_in[5];
  const int*   idx_j = (const int*)d_in[6];
  const float* W1r   = (const float*)d_in[7];
  const float* b1r   = (const float*)d_in[8];
  const float* W2r   = (const float*)d_in[9];
  const float* b2r   = (const float*)d_in[10];
  const float* W1s   = (const float*)d_in[11];
  const float* b1s   = (const float*)d_in[12];
  const float* W2s   = (const float*)d_in[13];
  const float* b2s   = (const float*)d_in[14];
  const float* Wq    = (const float*)d_in[15];
  const float* Wk    = (const float*)d_in[16];
  const float* Wv    = (const float*)d_in[17];
  float* out = (float*)d_out;
  char* ws = (char*)d_ws;
  unsigned short* q_ws  = (unsigned short*)(ws + 0);          // 11.2 MB
  unsigned short* k_ws  = (unsigned short*)(ws + 11200000);   // 11.2 MB
  unsigned short* v_ws  = (unsigned short*)(ws + 22400000);   // 11.2 MB
  float* alpha_ws       = (float*)(ws + 33600000);            // 11.2 MB
  int* rs               = (int*)(ws + 44800000);              // 100,004 B
  unsigned short* W1sw  = (unsigned short*)(ws + 44900016);   // 28,672 B
  unsigned short* W2sw  = (unsigned short*)(ws + 44928688);   // 100,352 B

  k_pre<<<dim3(NBNODE + 1563 + 3), dim3(256), 0, stream>>>(
      x, Wq, Wk, Wv, idx_i, W1r, W1s, b1r, b1s, W2r, W2s,
      q_ws, k_ws, v_ws, rs, W1sw, W2sw);
  k_edge<<<dim3(1024), dim3(256), 0, stream>>>(
      rbf, cut, ev, idx_i, idx_j, W1sw, W2sw, b1r, b2r, b2s,
      q_ws, k_ws, alpha_ws);
  k_agg<<<dim3(6250), dim3(256), 0, stream>>>(
      alpha_ws, v_ws, ylm, idx_j, rs, out);
}

// Round 11
// 577.738 us; speedup vs baseline: 2.2002x; 2.2002x over previous
//
#include <hip/hip_runtime.h>
#include <hip/hip_bf16.h>

// Problem constants (from reference)
#define NNODE 25000
#define PEDGE 400000
#define FDIM  224      // F = TF = 224; q/k: 7 heads x 32, v: 4 heads x 56
#define NORD  15
#define NXOUT (NNODE*FDIM)
#define NTILE2 6250    // PEDGE/64 (64-edge block tiles)

typedef __bf16 bf16x8 __attribute__((ext_vector_type(8)));
typedef short  s16x8  __attribute__((ext_vector_type(8)));
typedef float  f32x4  __attribute__((ext_vector_type(4)));

// MFMA wrapper: tolerate either v8bf16 or v8i16 builtin signature across ROCm versions.
template <typename V>
__device__ __forceinline__ auto mfma_impl(V a, V b, f32x4 c, int)
    -> decltype(__builtin_amdgcn_mfma_f32_16x16x32_bf16(a, b, c, 0, 0, 0)) {
  return __builtin_amdgcn_mfma_f32_16x16x32_bf16(a, b, c, 0, 0, 0);
}
template <typename V>
__device__ __forceinline__ f32x4 mfma_impl(V a, V b, f32x4 c, long) {
  return __builtin_amdgcn_mfma_f32_16x16x32_bf16(
      __builtin_bit_cast(s16x8, a), __builtin_bit_cast(s16x8, b), c, 0, 0, 0);
}
__device__ __forceinline__ f32x4 MFMA_BF16(bf16x8 a, bf16x8 b, f32x4 c) {
  return mfma_impl(a, b, c, 0);
}

__device__ __forceinline__ float siluf(float x) { return x / (1.0f + __expf(-x)); }
__device__ __forceinline__ unsigned short f2bf(float x) {
  __hip_bfloat16 h = __float2bfloat16(x);
  return __builtin_bit_cast(unsigned short, h);
}
__device__ __forceinline__ float bf2f(unsigned short u) {
  unsigned int v = ((unsigned int)u) << 16;
  return __builtin_bit_cast(float, v);
}

// DPP 16-lane row sum on the VALU pipe.
template <int CTRL>
__device__ __forceinline__ float dpp_radd(float v) {
  int s = __builtin_amdgcn_update_dpp(0, __builtin_bit_cast(int, v), CTRL, 0xf, 0xf, true);
  return v + __builtin_bit_cast(float, s);
}
__device__ __forceinline__ float row16_sum(float v) {
  v = dpp_radd<0xB1>(v);    // quad_perm [1,0,3,2]  (xor 1)
  v = dpp_radd<0x4E>(v);    // quad_perm [2,3,0,1]  (xor 2)
  v = dpp_radd<0x124>(v);   // row_ror:4
  v = dpp_radd<0x128>(v);   // row_ror:8
  return v;                 // all 16 lanes of the row hold the sum
}

// ---------------------------------------------------------------------------
// k_pre: (a) node q,k,v projections, 8 nodes/block, weights in registers;
//        (b) CSR row_start from sorted idx_i;
//        (c) W1cat (64x224 block-diag + bias row 35) -> swizzled bf16 (global)
//        (d) W2cat (224x224) -> swizzled bf16 (global)
// ---------------------------------------------------------------------------
#define NPB 8
#define NBNODE 3125   // 25000/8
__global__ __launch_bounds__(256) void k_pre(
    const float* __restrict__ x, const float* __restrict__ Wq,
    const float* __restrict__ Wk, const float* __restrict__ Wv,
    const int* __restrict__ idx_i,
    const float* __restrict__ W1r, const float* __restrict__ W1s,
    const float* __restrict__ b1r, const float* __restrict__ b1s,
    const float* __restrict__ W2r, const float* __restrict__ W2s,
    unsigned short* __restrict__ q_ws, unsigned short* __restrict__ k_ws,
    unsigned short* __restrict__ v_ws, int* __restrict__ rs,
    unsigned short* __restrict__ W1sw, unsigned short* __restrict__ W2sw) {
  int b = blockIdx.x, t = threadIdx.x;
  if (b < NBNODE) {
    __shared__ float xs[NPB * FDIM];           // 7,168 B
    int n0 = b * NPB;
    const float4* x4 = (const float4*)(x + n0 * FDIM);
    float4* xs4 = (float4*)xs;
    for (int i = t; i < NPB * (FDIM/4); i += 256) xs4[i] = x4[i];
    float wq[32], wk[32], wv[56];
    int h = 0, d = 0;
    if (t < FDIM) {
      #pragma unroll
      for (int j = 0; j < 32; j++) { wq[j] = Wq[t*32 + j]; wk[j] = Wk[t*32 + j]; }
      h = t / 56; d = t - h*56;
      #pragma unroll
      for (int j = 0; j < 56; j++) wv[j] = Wv[(h*56 + d)*56 + j];
    }
    __syncthreads();
    if (t < FDIM) {
      int qh = t >> 5;
      #pragma unroll
      for (int m = 0; m < NPB; m++) {
        const float* xr = xs + m*FDIM;
        const float* xh = xr + (qh << 5);
        float aq = 0.f, ak = 0.f;
        #pragma unroll
        for (int j = 0; j < 32; j++) { aq += wq[j]*xh[j]; ak += wk[j]*xh[j]; }
        int n = n0 + m;
        q_ws[n*FDIM + t] = f2bf(siluf(aq));
        k_ws[n*FDIM + t] = f2bf(siluf(ak));
        const float* xv = xr + h*56;
        float av = 0.f;
        #pragma unroll
        for (int j = 0; j < 56; j++) av += wv[j]*xv[j];
        v_ws[n*FDIM + t] = f2bf(av);   // no silu on v
      }
    }
  } else if (b < NBNODE + 1563) {
    int p = (b - NBNODE)*256 + t;
    if (p < PEDGE) {
      int cur = idx_i[p];
      if (p == 0) { for (int v = 0; v <= cur; v++) rs[v] = 0; }
      else { int prev = idx_i[p-1]; for (int v = prev+1; v <= cur; v++) rs[v] = p; }
      if (p == PEDGE-1) { for (int v = cur+1; v <= NNODE; v++) rs[v] = PEDGE; }
    }
  } else if (b == NBNODE + 1563) {
    // W1cat[row<64][col<224]; row 35 = b1cat (bias folded into GEMM)
    for (int lin = t; lin < 64*224; lin += 256) {
      int row = lin / 224, col = lin - row*224;
      float v = 0.f;
      if (row < 32) { if (col < 112) v = W1r[row*112 + col]; }
      else if (row < 35) { if (col >= 112) v = W1s[(row-32)*112 + (col-112)]; }
      else if (row == 35) v = (col < 112) ? b1r[col] : b1s[col-112];
      int nt = col >> 4, lanelo = col & 15, k = row >> 5, hi = (row >> 3) & 3, j = row & 7;
      W1sw[(((nt*2 + k)*64) + hi*16 + lanelo)*8 + j] = f2bf(v);
    }
  } else {
    // W2cat (224x224) -> swizzled global, output-linear (coalesced writes)
    int half = b - (NBNODE + 1564);      // 0 or 1
    int o0 = half * 25088;
    for (int o = o0 + t; o < o0 + 25088; o += 256) {
      int j = o & 7, lane = (o >> 3) & 63, rest = o >> 9;
      int hi = lane >> 4, lanelo = lane & 15;
      int k32 = rest % 7, nt = rest / 7;
      int row = k32*32 + hi*8 + j, col = nt*16 + lanelo;
      float v = (row < 112) ? W2r[row*224 + col] : W2s[(row-112)*224 + col];
      W2sw[o] = f2bf(v);
    }
  }
}

// ---------------------------------------------------------------------------
// k_edge R14: R13's no-hoist h-outer epilogue at R12's verified 16-edge/wave
// geometry.
//
// R13's correctness failure was pure geometry: full-width h1 (224 cols) was
// written with HSTRIDE=136 -> rows overflowed into each other and into the
// next wave's slice. Full-width h1 needs stride 232; at 32 edges/wave that
// is 59.4 KB (2 blocks/CU — the R0 occupancy trap). So: 16 edges/wave
// (R12's tile, layer-1 verified passing), LDS = 64x232x2 = 29,696 B ->
// 4 blocks/CU, 50% occ at (256,4).
//   - aa never hoisted: A-fragments re-read from LDS per (hp,kt). h1 stays
//     bf16-live all of layer-2 (no wbuf, no TBAA fences).
//   - h-PAIRS: one a-read feeds 4 independent MFMA chains (nt=4hp..4hp+3),
//     16 acc regs (R10 lesson: 2-chain serial accumulate stalls MFMA pipe);
//     h=6 tail runs 2 chains.
//   - consumer in MFMA C-layout (R0/R12 verified): scalar q/k gathers (16
//     lanes read 32 contiguous bytes of one row -> coalesced), row16_sum.
//   - layer-1 block-diag halving (R12 verified): nt 0..6 u0-only + scalar
//     b1r; nt 7..13 u1-only (b1s via bias row u1[3]=1). 14 MFMAs.
// Persistent state ~45 regs -> fits the (256,4) 64-arch budget. Cost: W2
// L2 traffic doubles vs 32-edge tiles (weights L2-resident, cheap).
// Same-wave in-order LDS pipe orders layer-1 writes -> epilogue reads.
// Grid 1024; grid-stride over 6250 tiles.
// ---------------------------------------------------------------------------
#define HS2 232
__global__ __launch_bounds__(256, 4) void k_edge(
    const float* __restrict__ rbf, const float* __restrict__ cut,
    const float* __restrict__ ev,
    const int* __restrict__ idx_i, const int* __restrict__ idx_j,
    const unsigned short* __restrict__ W1sw,
    const unsigned short* __restrict__ W2sw,
    const float* __restrict__ b1r,
    const float* __restrict__ b2r, const float* __restrict__ b2s,
    const unsigned short* __restrict__ q_ws, const unsigned short* __restrict__ k_ws,
    float* __restrict__ alpha_ws) {
  __shared__ __bf16 h1s[64*HS2];    // 4 waves x 16 rows x 232 = 29,696 B
  int tid = threadIdx.x;
  int wave = tid >> 6, lane = tid & 63;
  int mrow = lane & 15, quad = lane >> 4;
  __bf16* h1w = h1s + wave*16*HS2;  // wave-private 16-row slice
  for (int T = blockIdx.x; T < NTILE2; T += gridDim.x) {
    int gbase = T*64 + wave*16;
    // ---- u fragments ----
    bf16x8 u0, u1;
    {
      int e = gbase + mrow;
      float cu = cut[e];
      const float4* r4 = (const float4*)(rbf + e*32 + quad*8);
      float4 v0 = r4[0], v1 = r4[1];
      u0[0] = (__bf16)(v0.x*cu); u0[1] = (__bf16)(v0.y*cu);
      u0[2] = (__bf16)(v0.z*cu); u0[3] = (__bf16)(v0.w*cu);
      u0[4] = (__bf16)(v1.x*cu); u0[5] = (__bf16)(v1.y*cu);
      u0[6] = (__bf16)(v1.z*cu); u0[7] = (__bf16)(v1.w*cu);
      #pragma unroll
      for (int j = 0; j < 8; j++) u1[j] = (__bf16)0.f;
      if (quad == 0) {   // k = 32..35: l0 contraction + bias row (k=35)
        int ie = idx_i[e], je = idx_j[e];
        const float* evi = ev + ie*NORD; const float* evj = ev + je*NORD;
        float s0 = 0.f, s1 = 0.f, s2 = 0.f;
        #pragma unroll
        for (int o = 0; o < 3; o++)  { float dd = evj[o]-evi[o]; s0 += dd*dd; }
        #pragma unroll
        for (int o = 3; o < 8; o++)  { float dd = evj[o]-evi[o]; s1 += dd*dd; }
        #pragma unroll
        for (int o = 8; o < 15; o++) { float dd = evj[o]-evi[o]; s2 += dd*dd; }
        u1[0] = (__bf16)s0; u1[1] = (__bf16)s1; u1[2] = (__bf16)s2;
        u1[3] = (__bf16)1.0f;   // bias row k=35
      }
    }
    // ---- layer 1 (block-diag halved): nt 0..6 u0-only + scalar b1r ----
    #pragma unroll
    for (int nt = 0; nt < 7; nt++) {
      bf16x8 b0 = *(const bf16x8*)(W1sw + ((nt*2 + 0)*64 + lane)*8);
      float bv1 = b1r[nt*16 + mrow];
      f32x4 acc = {bv1, bv1, bv1, bv1};
      acc = MFMA_BF16(u0, b0, acc);
      #pragma unroll
      for (int r = 0; r < 4; r++)
        h1w[(quad*4 + r)*HS2 + nt*16 + mrow] = (__bf16)siluf(acc[r]);
    }
    // ---- layer 1: nt 7..13 u1-only (b1s via bias row) ----
    #pragma unroll
    for (int nt = 7; nt < 14; nt++) {
      bf16x8 b1 = *(const bf16x8*)(W1sw + ((nt*2 + 1)*64 + lane)*8);
      f32x4 acc = {0.f, 0.f, 0.f, 0.f};
      acc = MFMA_BF16(u1, b1, acc);
      #pragma unroll
      for (int r = 0; r < 4; r++)
        h1w[(quad*4 + r)*HS2 + nt*16 + mrow] = (__bf16)siluf(acc[r]);
    }
    // ---- owned-edge metadata (C-layout rows = quad*4+r) ----
    int ii[4], jj[4]; float cc[4];
    #pragma unroll
    for (int r = 0; r < 4; r++) {
      int ee = gbase + quad*4 + r;
      ii[r] = idx_i[ee]; jj[r] = idx_j[ee]; cc[r] = cut[ee];
    }
    // ---- layer 2 + alpha: h-pairs; a-fragment re-read per kt feeds 4
    //      independent MFMA chains (same-wave RAW through LDS) ----
    #pragma unroll 1
    for (int hp = 0; hp < 3; hp++) {
      int nt0 = hp*4;
      int cg0 = (nt0 + 0)*16 + mrow;
      int cg1 = (nt0 + 1)*16 + mrow;
      int cg2 = (nt0 + 2)*16 + mrow;
      int cg3 = (nt0 + 3)*16 + mrow;
      float bv0 = b2r[cg0] + b2s[cg0];
      float bv1 = b2r[cg1] + b2s[cg1];
      float bv2 = b2r[cg2] + b2s[cg2];
      float bv3 = b2r[cg3] + b2s[cg3];
      f32x4 acc0 = {bv0, bv0, bv0, bv0};
      f32x4 acc1 = {bv1, bv1, bv1, bv1};
      f32x4 acc2 = {bv2, bv2, bv2, bv2};
      f32x4 acc3 = {bv3, bv3, bv3, bv3};
      #pragma unroll
      for (int kt = 0; kt < 7; kt++) {
        bf16x8 a = *(const bf16x8*)&h1w[mrow*HS2 + kt*32 + quad*8];
        bf16x8 bb0 = *(const bf16x8*)(W2sw + (((nt0+0)*7 + kt)*64 + lane)*8);
        bf16x8 bb1 = *(const bf16x8*)(W2sw + (((nt0+1)*7 + kt)*64 + lane)*8);
        bf16x8 bb2 = *(const bf16x8*)(W2sw + (((nt0+2)*7 + kt)*64 + lane)*8);
        bf16x8 bb3 = *(const bf16x8*)(W2sw + (((nt0+3)*7 + kt)*64 + lane)*8);
        acc0 = MFMA_BF16(a, bb0, acc0);
        acc1 = MFMA_BF16(a, bb1, acc1);
        acc2 = MFMA_BF16(a, bb2, acc2);
        acc3 = MFMA_BF16(a, bb3, acc3);
      }
      #pragma unroll
      for (int r = 0; r < 4; r++) {
        float p0 = acc0[r] * bf2f(q_ws[ii[r]*FDIM + cg0]) * bf2f(k_ws[jj[r]*FDIM + cg0])
                 + acc1[r] * bf2f(q_ws[ii[r]*FDIM + cg1]) * bf2f(k_ws[jj[r]*FDIM + cg1]);
        float p1 = acc2[r] * bf2f(q_ws[ii[r]*FDIM + cg2]) * bf2f(k_ws[jj[r]*FDIM + cg2])
                 + acc3[r] * bf2f(q_ws[ii[r]*FDIM + cg3]) * bf2f(k_ws[jj[r]*FDIM + cg3]);
        float v0 = row16_sum(p0);
        float v1 = row16_sum(p1);
        if (mrow == 0) {
          int eo = gbase + quad*4 + r;
          alpha_ws[eo*7 + hp*2]     = v0 * cc[r];
          alpha_ws[eo*7 + hp*2 + 1] = v1 * cc[r];
        }
      }
    }
    // ---- tail h = 6 (nt 12,13): 2 chains ----
    {
      int cg0 = 12*16 + mrow, cg1 = 13*16 + mrow;
      float bv0 = b2r[cg0] + b2s[cg0];
      float bv1 = b2r[cg1] + b2s[cg1];
      f32x4 acc0 = {bv0, bv0, bv0, bv0};
      f32x4 acc1 = {bv1, bv1, bv1, bv1};
      #pragma unroll
      for (int kt = 0; kt < 7; kt++) {
        bf16x8 a = *(const bf16x8*)&h1w[mrow*HS2 + kt*32 + quad*8];
        bf16x8 bb0 = *(const bf16x8*)(W2sw + ((12*7 + kt)*64 + lane)*8);
        bf16x8 bb1 = *(const bf16x8*)(W2sw + ((13*7 + kt)*64 + lane)*8);
        acc0 = MFMA_BF16(a, bb0, acc0);
        acc1 = MFMA_BF16(a, bb1, acc1);
      }
      #pragma unroll
      for (int r = 0; r < 4; r++) {
        float p = acc0[r] * bf2f(q_ws[ii[r]*FDIM + cg0]) * bf2f(k_ws[jj[r]*FDIM + cg0])
                + acc1[r] * bf2f(q_ws[ii[r]*FDIM + cg1]) * bf2f(k_ws[jj[r]*FDIM + cg1]);
        float v = row16_sum(p);
        if (mrow == 0) alpha_ws[(gbase + quad*4 + r)*7 + 6] = v * cc[r];
      }
    }
  }
}

// ---------------------------------------------------------------------------
// k_agg: one wave per node; 4-wide v loads; unrolled x2; zeros for empty segs.
// ---------------------------------------------------------------------------
__global__ __launch_bounds__(256) void k_agg(
    const float* __restrict__ alpha_ws, const unsigned short* __restrict__ v_ws,
    const float* __restrict__ ylm, const int* __restrict__ idx_j,
    const int* __restrict__ rs, float* __restrict__ out) {
  int n = blockIdx.x*4 + (threadIdx.x >> 6);
  if (n >= NNODE) return;
  int lane = threadIdx.x & 63;
  int s = rs[n], e = rs[n+1];
  if (lane < 56) {
    int c = lane*4, h = lane/14;      // 4 cols per lane, same head (56%4==0)
    float ax = 0.f, ay = 0.f, az = 0.f, aw = 0.f;
    int p = s;
    for (; p + 1 < e; p += 2) {
      int j0 = idx_j[p], j1 = idx_j[p+1];
      float a0 = alpha_ws[p*7 + h], a1 = alpha_ws[(p+1)*7 + h];
      ushort4 w0 = *(const ushort4*)(v_ws + j0*FDIM + c);
      ushort4 w1 = *(const ushort4*)(v_ws + j1*FDIM + c);
      ax += a0*bf2f(w0.x) + a1*bf2f(w1.x);
      ay += a0*bf2f(w0.y) + a1*bf2f(w1.y);
      az += a0*bf2f(w0.z) + a1*bf2f(w1.z);
      aw += a0*bf2f(w0.w) + a1*bf2f(w1.w);
    }
    if (p < e) {
      int j0 = idx_j[p];
      float a0 = alpha_ws[p*7 + h];
      ushort4 w0 = *(const ushort4*)(v_ws + j0*FDIM + c);
      ax += a0*bf2f(w0.x); ay += a0*bf2f(w0.y);
      az += a0*bf2f(w0.z); aw += a0*bf2f(w0.w);
    }
    float4 o4 = {ax, ay, az, aw};
    *(float4*)(out + n*FDIM + c) = o4;
  } else {
    int o = lane - 56;                // 0..7 ; second col o+8 (8..14)
    int dg0 = (o < 3) ? 0 : ((o < 8) ? 1 : 2);
    float a0 = 0.f, a1 = 0.f;
    for (int p = s; p < e; p++) {
      const float* ap = alpha_ws + p*7 + 4;
      a0 += ap[dg0] * ylm[p*NORD + o];
      if (o < 7) a1 += ap[2] * ylm[p*NORD + o + 8];
    }
    out[NXOUT + n*NORD + o] = a0;
    if (o < 7) out[NXOUT + n*NORD + o + 8] = a1;
  }
}

extern "C" void kernel_launch(void* const* d_in, const int* in_sizes, int n_in,
                              void* d_out, int out_size, void* d_ws, size_t ws_size,
                              hipStream_t stream) {
  const float* x     = (const float*)d_in[0];
  const float* ev    = (const float*)d_in[1];
  const float* rbf   = (const float*)d_in[2];
  const float* ylm   = (const float*)d_in[3];
  const float* cut   = (const float*)d_in[4];
  const int*   idx_i = (const int*)d_in[5];
  const int*   idx_j = (const int*)d_in[6];
  const float* W1r   = (const float*)d_in[7];
  const float* b1r   = (const float*)d_in[8];
  const float* W2r   = (const float*)d_in[9];
  const float* b2r   = (const float*)d_in[10];
  const float* W1s   = (const float*)d_in[11];
  const float* b1s   = (const float*)d_in[12];
  const float* W2s   = (const float*)d_in[13];
  const float* b2s   = (const float*)d_in[14];
  const float* Wq    = (const float*)d_in[15];
  const float* Wk    = (const float*)d_in[16];
  const float* Wv    = (const float*)d_in[17];
  float* out = (float*)d_out;
  char* ws = (char*)d_ws;
  unsigned short* q_ws  = (unsigned short*)(ws + 0);          // 11.2 MB
  unsigned short* k_ws  = (unsigned short*)(ws + 11200000);   // 11.2 MB
  unsigned short* v_ws  = (unsigned short*)(ws + 22400000);   // 11.2 MB
  float* alpha_ws       = (float*)(ws + 33600000);            // 11.2 MB
  int* rs               = (int*)(ws + 44800000);              // 100,004 B
  unsigned short* W1sw  = (unsigned short*)(ws + 44900016);   // 28,672 B
  unsigned short* W2sw  = (unsigned short*)(ws + 44928688);   // 100,352 B

  k_pre<<<dim3(NBNODE + 1563 + 3), dim3(256), 0, stream>>>(
      x, Wq, Wk, Wv, idx_i, W1r, W1s, b1r, b1s, W2r, W2s,
      q_ws, k_ws, v_ws, rs, W1sw, W2sw);
  k_edge<<<dim3(1024), dim3(256), 0, stream>>>(
      rbf, cut, ev, idx_i, idx_j, W1sw, W2sw, b1r, b2r, b2s,
      q_ws, k_ws, alpha_ws);
  k_agg<<<dim3(6250), dim3(256), 0, stream>>>(
      alpha_ws, v_ws, ylm, idx_j, rs, out);
}

// Round 12
// 466.516 us; speedup vs baseline: 2.7248x; 1.2384x over previous
//
#include <hip/hip_runtime.h>
#include <hip/hip_bf16.h>

// Problem constants (from reference)
#define NNODE 25000
#define PEDGE 400000
#define FDIM  224      // F = TF = 224; q/k: 7 heads x 32, v: 4 heads x 56
#define NORD  15
#define NXOUT (NNODE*FDIM)
#define NTILE 3125     // PEDGE/128 (exact)

typedef __bf16 bf16x8 __attribute__((ext_vector_type(8)));
typedef short  s16x8  __attribute__((ext_vector_type(8)));
typedef float  f32x4  __attribute__((ext_vector_type(4)));
typedef unsigned short u16x8 __attribute__((ext_vector_type(8)));

// MFMA wrapper: tolerate either v8bf16 or v8i16 builtin signature across ROCm versions.
template <typename V>
__device__ __forceinline__ auto mfma_impl(V a, V b, f32x4 c, int)
    -> decltype(__builtin_amdgcn_mfma_f32_16x16x32_bf16(a, b, c, 0, 0, 0)) {
  return __builtin_amdgcn_mfma_f32_16x16x32_bf16(a, b, c, 0, 0, 0);
}
template <typename V>
__device__ __forceinline__ f32x4 mfma_impl(V a, V b, f32x4 c, long) {
  return __builtin_amdgcn_mfma_f32_16x16x32_bf16(
      __builtin_bit_cast(s16x8, a), __builtin_bit_cast(s16x8, b), c, 0, 0, 0);
}
__device__ __forceinline__ f32x4 MFMA_BF16(bf16x8 a, bf16x8 b, f32x4 c) {
  return mfma_impl(a, b, c, 0);
}

__device__ __forceinline__ float siluf(float x) { return x / (1.0f + __expf(-x)); }
__device__ __forceinline__ unsigned short f2bf(float x) {
  __hip_bfloat16 h = __float2bfloat16(x);
  return __builtin_bit_cast(unsigned short, h);
}
__device__ __forceinline__ float bf2f(unsigned short u) {
  unsigned int v = ((unsigned int)u) << 16;
  return __builtin_bit_cast(float, v);
}

// DPP add on the VALU pipe.
template <int CTRL>
__device__ __forceinline__ float dpp_radd(float v) {
  int s = __builtin_amdgcn_update_dpp(0, __builtin_bit_cast(int, v), CTRL, 0xf, 0xf, true);
  return v + __builtin_bit_cast(float, s);
}

// ---------------------------------------------------------------------------
// k_pre: (a) node q,k,v projections, 8 nodes/block, weights in registers;
//        (b) CSR row_start from sorted idx_i;
//        (c) W1cat (64x224 block-diag + bias row 35) -> swizzled bf16 (global)
//        (d) W2cat (224x224) -> swizzled bf16 (global)
// ---------------------------------------------------------------------------
#define NPB 8
#define NBNODE 3125   // 25000/8
__global__ __launch_bounds__(256) void k_pre(
    const float* __restrict__ x, const float* __restrict__ Wq,
    const float* __restrict__ Wk, const float* __restrict__ Wv,
    const int* __restrict__ idx_i,
    const float* __restrict__ W1r, const float* __restrict__ W1s,
    const float* __restrict__ b1r, const float* __restrict__ b1s,
    const float* __restrict__ W2r, const float* __restrict__ W2s,
    unsigned short* __restrict__ q_ws, unsigned short* __restrict__ k_ws,
    unsigned short* __restrict__ v_ws, int* __restrict__ rs,
    unsigned short* __restrict__ W1sw, unsigned short* __restrict__ W2sw) {
  int b = blockIdx.x, t = threadIdx.x;
  if (b < NBNODE) {
    __shared__ float xs[NPB * FDIM];           // 7,168 B
    int n0 = b * NPB;
    const float4* x4 = (const float4*)(x + n0 * FDIM);
    float4* xs4 = (float4*)xs;
    for (int i = t; i < NPB * (FDIM/4); i += 256) xs4[i] = x4[i];
    float wq[32], wk[32], wv[56];
    int h = 0, d = 0;
    if (t < FDIM) {
      #pragma unroll
      for (int j = 0; j < 32; j++) { wq[j] = Wq[t*32 + j]; wk[j] = Wk[t*32 + j]; }
      h = t / 56; d = t - h*56;
      #pragma unroll
      for (int j = 0; j < 56; j++) wv[j] = Wv[(h*56 + d)*56 + j];
    }
    __syncthreads();
    if (t < FDIM) {
      int qh = t >> 5;
      #pragma unroll
      for (int m = 0; m < NPB; m++) {
        const float* xr = xs + m*FDIM;
        const float* xh = xr + (qh << 5);
        float aq = 0.f, ak = 0.f;
        #pragma unroll
        for (int j = 0; j < 32; j++) { aq += wq[j]*xh[j]; ak += wk[j]*xh[j]; }
        int n = n0 + m;
        q_ws[n*FDIM + t] = f2bf(siluf(aq));
        k_ws[n*FDIM + t] = f2bf(siluf(ak));
        const float* xv = xr + h*56;
        float av = 0.f;
        #pragma unroll
        for (int j = 0; j < 56; j++) av += wv[j]*xv[j];
        v_ws[n*FDIM + t] = f2bf(av);   // no silu on v
      }
    }
  } else if (b < NBNODE + 1563) {
    int p = (b - NBNODE)*256 + t;
    if (p < PEDGE) {
      int cur = idx_i[p];
      if (p == 0) { for (int v = 0; v <= cur; v++) rs[v] = 0; }
      else { int prev = idx_i[p-1]; for (int v = prev+1; v <= cur; v++) rs[v] = p; }
      if (p == PEDGE-1) { for (int v = cur+1; v <= NNODE; v++) rs[v] = PEDGE; }
    }
  } else if (b == NBNODE + 1563) {
    // W1cat[row<64][col<224]; row 35 = b1cat (bias folded into GEMM)
    for (int lin = t; lin < 64*224; lin += 256) {
      int row = lin / 224, col = lin - row*224;
      float v = 0.f;
      if (row < 32) { if (col < 112) v = W1r[row*112 + col]; }
      else if (row < 35) { if (col >= 112) v = W1s[(row-32)*112 + (col-112)]; }
      else if (row == 35) v = (col < 112) ? b1r[col] : b1s[col-112];
      int nt = col >> 4, lanelo = col & 15, k = row >> 5, hi = (row >> 3) & 3, j = row & 7;
      W1sw[(((nt*2 + k)*64) + hi*16 + lanelo)*8 + j] = f2bf(v);
    }
  } else {
    // W2cat (224x224) -> swizzled global, output-linear (coalesced writes)
    int half = b - (NBNODE + 1564);      // 0 or 1
    int o0 = half * 25088;
    for (int o = o0 + t; o < o0 + 25088; o += 256) {
      int j = o & 7, lane = (o >> 3) & 63, rest = o >> 9;
      int hi = lane >> 4, lanelo = lane & 15;
      int k32 = rest % 7, nt = rest / 7;
      int row = k32*32 + hi*8 + j, col = nt*16 + lanelo;
      float v = (row < 112) ? W2r[row*224 + col] : W2s[(row-112)*224 + col];
      W2sw[o] = f2bf(v);
    }
  }
}

// ---------------------------------------------------------------------------
// k_edge R15 = R9 exact (measured 219 us, best of 6 structures) + the ONE
// verified orthogonal improvement: block-diagonal layer-1 halving.
//
// R9 recap (measured): h-outer epilogue with producer->wbuf->consumer, 32
// edges/wave, HSTRIDE=136 two-stage column split, (256,4), occ 40%. It
// spills ~280 MB/dispatch (aa[2][7]=56 persistent regs over the 64-arch
// budget) yet BEATS every restructure tried since: mg-split (R10, lost bb
// sharing), K-split (R11, paid global RMW), kt-outer AGPR acc (R12,
// accumulator spill per-iteration), no-hoist LDS re-read (R14, scheduler
// pipelines 28 bb loads -> worse spills). Lesson: occupancy 40% + 2-chain
// bb-shared ILP dominates; accept the one-time aa spill.
//
// R15 change (layer-1 ONLY; epilogue byte-identical to R9): W1cat is
// block-diagonal — cols 0..111 depend only on u0 (rbf), cols 112..223 only
// on u1 (ev l0-contraction). Within R9's two stages:
//   stage A: nt 0..6 u0-only + scalar b1r bias; nt 7 u1-only (bias row).
//   stage B: nt 8..13 u1-only (b1s via bias row u1[3]=1).
// 28 layer-1 MFMAs instead of 56; 14 W1sw loads instead of 28. Verified
// passing in R11/R12/R14.
// ---------------------------------------------------------------------------
#define HSTRIDE 136
#define WSTRIDE 36
__global__ __launch_bounds__(256, 4) void k_edge(
    const float* __restrict__ rbf, const float* __restrict__ cut,
    const float* __restrict__ ev,
    const int* __restrict__ idx_i, const int* __restrict__ idx_j,
    const unsigned short* __restrict__ W1sw,
    const unsigned short* __restrict__ W2sw,
    const float* __restrict__ b1r,
    const float* __restrict__ b2r, const float* __restrict__ b2s,
    const unsigned short* __restrict__ q_ws, const unsigned short* __restrict__ k_ws,
    float* __restrict__ alpha_ws) {
  __shared__ __bf16 h1s[128*HSTRIDE];    // 34,816 B
  int tid = threadIdx.x;
  int wave = tid >> 6, lane = tid & 63;
  int mrow = lane & 15, quad = lane >> 4;
  int ed = lane >> 1, hh = lane & 1;
  float* wbuf = (float*)(h1s + wave*32*HSTRIDE);   // wave-private 8,704 B slice
  for (int T = blockIdx.x; T < NTILE; T += gridDim.x) {
    int base = T*128 + wave*32;
    // ---- u A-fragments: lane holds edge mrow (per mg), k-chunk quad*8+j ----
    bf16x8 u0[2], u1[2];
    #pragma unroll
    for (int mg = 0; mg < 2; mg++) {
      int e = base + mg*16 + mrow;
      float cu = cut[e];
      const float4* r4 = (const float4*)(rbf + e*32 + quad*8);
      float4 v0 = r4[0], v1 = r4[1];
      u0[mg][0] = (__bf16)(v0.x*cu); u0[mg][1] = (__bf16)(v0.y*cu);
      u0[mg][2] = (__bf16)(v0.z*cu); u0[mg][3] = (__bf16)(v0.w*cu);
      u0[mg][4] = (__bf16)(v1.x*cu); u0[mg][5] = (__bf16)(v1.y*cu);
      u0[mg][6] = (__bf16)(v1.z*cu); u0[mg][7] = (__bf16)(v1.w*cu);
      #pragma unroll
      for (int j = 0; j < 8; j++) u1[mg][j] = (__bf16)0.f;
      if (quad == 0) {   // k = 32..35: l0 contraction + bias row (k=35)
        int ie = idx_i[e], je = idx_j[e];
        const float* evi = ev + ie*NORD; const float* evj = ev + je*NORD;
        float s0 = 0.f, s1 = 0.f, s2 = 0.f;
        #pragma unroll
        for (int o = 0; o < 3; o++)  { float dd = evj[o]-evi[o]; s0 += dd*dd; }
        #pragma unroll
        for (int o = 3; o < 8; o++)  { float dd = evj[o]-evi[o]; s1 += dd*dd; }
        #pragma unroll
        for (int o = 8; o < 15; o++) { float dd = evj[o]-evi[o]; s2 += dd*dd; }
        u1[mg][0] = (__bf16)s0; u1[mg][1] = (__bf16)s1; u1[mg][2] = (__bf16)s2;
        u1[mg][3] = (__bf16)1.0f;   // bias row k=35
      }
    }
    bf16x8 aa[2][7];
    // ---- layer 1 stage A (block-diag): nt 0..6 u0-only + scalar b1r;
    //      nt 7 u1-only (bias row). cols 0..127 ----
    #pragma unroll
    for (int nt = 0; nt < 7; nt++) {
      bf16x8 b0 = *(const bf16x8*)(W1sw + ((nt*2 + 0)*64 + lane)*8);
      float bv1 = b1r[nt*16 + mrow];
      int colg = nt*16 + mrow;
      #pragma unroll
      for (int mg = 0; mg < 2; mg++) {
        f32x4 acc = {bv1, bv1, bv1, bv1};
        acc = MFMA_BF16(u0[mg], b0, acc);
        int rowb = wave*32 + mg*16 + quad*4;
        #pragma unroll
        for (int r = 0; r < 4; r++)
          h1s[(rowb + r)*HSTRIDE + colg] = (__bf16)siluf(acc[r]);
      }
    }
    {
      int nt = 7;
      bf16x8 b1 = *(const bf16x8*)(W1sw + ((nt*2 + 1)*64 + lane)*8);
      int colg = nt*16 + mrow;
      #pragma unroll
      for (int mg = 0; mg < 2; mg++) {
        f32x4 acc = {0.f, 0.f, 0.f, 0.f};
        acc = MFMA_BF16(u1[mg], b1, acc);
        int rowb = wave*32 + mg*16 + quad*4;
        #pragma unroll
        for (int r = 0; r < 4; r++)
          h1s[(rowb + r)*HSTRIDE + colg] = (__bf16)siluf(acc[r]);
      }
    }
    // ---- aa[*][0..3] (same-wave RAW through LDS; lgkmcnt orders) ----
    #pragma unroll
    for (int mg = 0; mg < 2; mg++) {
      int rowa = wave*32 + mg*16 + mrow;
      #pragma unroll
      for (int kt = 0; kt < 4; kt++)
        aa[mg][kt] = *(const bf16x8*)&h1s[rowa*HSTRIDE + kt*32 + quad*8];
    }
    // ---- layer 1 stage B (block-diag): nt 8..13 u1-only -> cols 0..95
    //      (buffer reuse; WAR ordered by same-wave in-order LDS pipe) ----
    #pragma unroll
    for (int nt = 8; nt < 14; nt++) {
      bf16x8 b1 = *(const bf16x8*)(W1sw + ((nt*2 + 1)*64 + lane)*8);
      int colg = (nt-8)*16 + mrow;
      #pragma unroll
      for (int mg = 0; mg < 2; mg++) {
        f32x4 acc = {0.f, 0.f, 0.f, 0.f};
        acc = MFMA_BF16(u1[mg], b1, acc);
        int rowb = wave*32 + mg*16 + quad*4;
        #pragma unroll
        for (int r = 0; r < 4; r++)
          h1s[(rowb + r)*HSTRIDE + colg] = (__bf16)siluf(acc[r]);
      }
    }
    // ---- aa[*][4..6] ----
    #pragma unroll
    for (int mg = 0; mg < 2; mg++) {
      int rowa = wave*32 + mg*16 + mrow;
      #pragma unroll
      for (int kt = 4; kt < 7; kt++)
        aa[mg][kt] = *(const bf16x8*)&h1s[rowa*HSTRIDE + (kt-4)*32 + quad*8];
    }
    // fence: h1s (bf16) is about to be reused as f32 wbuf (TBAA boundary)
    asm volatile("" ::: "memory");
    // ---- owned-edge metadata for consumer phase ----
    int eo = base + ed;
    int io = idx_i[eo], jo = idx_j[eo];
    float co = cut[eo];
    const unsigned short* qrow = q_ws + io*FDIM + hh*16;
    const unsigned short* krow = k_ws + jo*FDIM + hh*16;
    // ---- layer 2 + alpha: per 32-col chunk h, MFMA -> wbuf -> per-edge dot
    #pragma unroll 1
    for (int h = 0; h < 7; h++) {
      // producer: w chunk (rows 0..31 = this wave's edges, cols 0..31)
      #pragma unroll
      for (int t2 = 0; t2 < 2; t2++) {
        int nt = h*2 + t2;
        int colg = nt*16 + mrow;
        float bv = b2r[colg] + b2s[colg];   // L1-resident
        f32x4 acc0 = {bv, bv, bv, bv}, acc1 = {bv, bv, bv, bv};
        #pragma unroll
        for (int kt = 0; kt < 7; kt++) {
          bf16x8 bb = *(const bf16x8*)(W2sw + ((nt*7 + kt)*64 + lane)*8);
          acc0 = MFMA_BF16(aa[0][kt], bb, acc0);
          acc1 = MFMA_BF16(aa[1][kt], bb, acc1);
        }
        int cw = t2*16 + mrow;
        #pragma unroll
        for (int r = 0; r < 4; r++) {
          wbuf[(quad*4 + r)*WSTRIDE + cw]      = acc0[r];
          wbuf[(16 + quad*4 + r)*WSTRIDE + cw] = acc1[r];
        }
      }
      // consumer: lane owns edge ed, cols [h*32 + hh*16, +16)
      const f32x4* wp = (const f32x4*)(wbuf + ed*WSTRIDE + hh*16);
      f32x4 w0 = wp[0], w1 = wp[1], w2 = wp[2], w3 = wp[3];
      u16x8 q0 = *(const u16x8*)(qrow + h*32);
      u16x8 q1 = *(const u16x8*)(qrow + h*32 + 8);
      u16x8 k0 = *(const u16x8*)(krow + h*32);
      u16x8 k1 = *(const u16x8*)(krow + h*32 + 8);
      float s = 0.f;
      #pragma unroll
      for (int j = 0; j < 4; j++) {
        s += w0[j] * (bf2f(q0[j])   * bf2f(k0[j]));
        s += w1[j] * (bf2f(q0[j+4]) * bf2f(k0[j+4]));
        s += w2[j] * (bf2f(q1[j])   * bf2f(k1[j]));
        s += w3[j] * (bf2f(q1[j+4]) * bf2f(k1[j+4]));
      }
      s = dpp_radd<0xB1>(s);     // pair-reduce (lane xor 1): full 32-col sum
      if (hh == 0) alpha_ws[eo*7 + h] = s * co;
    }
    // fence: next tile's bf16 h1 writes must not hoist above this tile's
    // f32 wbuf reads (same bytes, different TBAA types).
    asm volatile("" ::: "memory");
  }
}

// ---------------------------------------------------------------------------
// k_agg: one wave per node; 4-wide v loads; unrolled x2; zeros for empty segs.
// ---------------------------------------------------------------------------
__global__ __launch_bounds__(256) void k_agg(
    const float* __restrict__ alpha_ws, const unsigned short* __restrict__ v_ws,
    const float* __restrict__ ylm, const int* __restrict__ idx_j,
    const int* __restrict__ rs, float* __restrict__ out) {
  int n = blockIdx.x*4 + (threadIdx.x >> 6);
  if (n >= NNODE) return;
  int lane = threadIdx.x & 63;
  int s = rs[n], e = rs[n+1];
  if (lane < 56) {
    int c = lane*4, h = lane/14;      // 4 cols per lane, same head (56%4==0)
    float ax = 0.f, ay = 0.f, az = 0.f, aw = 0.f;
    int p = s;
    for (; p + 1 < e; p += 2) {
      int j0 = idx_j[p], j1 = idx_j[p+1];
      float a0 = alpha_ws[p*7 + h], a1 = alpha_ws[(p+1)*7 + h];
      ushort4 w0 = *(const ushort4*)(v_ws + j0*FDIM + c);
      ushort4 w1 = *(const ushort4*)(v_ws + j1*FDIM + c);
      ax += a0*bf2f(w0.x) + a1*bf2f(w1.x);
      ay += a0*bf2f(w0.y) + a1*bf2f(w1.y);
      az += a0*bf2f(w0.z) + a1*bf2f(w1.z);
      aw += a0*bf2f(w0.w) + a1*bf2f(w1.w);
    }
    if (p < e) {
      int j0 = idx_j[p];
      float a0 = alpha_ws[p*7 + h];
      ushort4 w0 = *(const ushort4*)(v_ws + j0*FDIM + c);
      ax += a0*bf2f(w0.x); ay += a0*bf2f(w0.y);
      az += a0*bf2f(w0.z); aw += a0*bf2f(w0.w);
    }
    float4 o4 = {ax, ay, az, aw};
    *(float4*)(out + n*FDIM + c) = o4;
  } else {
    int o = lane - 56;                // 0..7 ; second col o+8 (8..14)
    int dg0 = (o < 3) ? 0 : ((o < 8) ? 1 : 2);
    float a0 = 0.f, a1 = 0.f;
    for (int p = s; p < e; p++) {
      const float* ap = alpha_ws + p*7 + 4;
      a0 += ap[dg0] * ylm[p*NORD + o];
      if (o < 7) a1 += ap[2] * ylm[p*NORD + o + 8];
    }
    out[NXOUT + n*NORD + o] = a0;
    if (o < 7) out[NXOUT + n*NORD + o + 8] = a1;
  }
}

extern "C" void kernel_launch(void* const* d_in, const int* in_sizes, int n_in,
                              void* d_out, int out_size, void* d_ws, size_t ws_size,
                              hipStream_t stream) {
  const float* x     = (const float*)d_in[0];
  const float* ev    = (const float*)d_in[1];
  const float* rbf   = (const float*)d_in[2];
  const float* ylm   = (const float*)d_in[3];
  const float* cut   = (const float*)d_in[4];
  const int*   idx_i = (const int*)d_in[5];
  const int*   idx_j = (const int*)d_in[6];
  const float* W1r   = (const float*)d_in[7];
  const float* b1r   = (const float*)d_in[8];
  const float* W2r   = (const float*)d_in[9];
  const float* b2r   = (const float*)d_in[10];
  const float* W1s   = (const float*)d_in[11];
  const float* b1s   = (const float*)d_in[12];
  const float* W2s   = (const float*)d_in[13];
  const float* b2s   = (const float*)d_in[14];
  const float* Wq    = (const float*)d_in[15];
  const float* Wk    = (const float*)d_in[16];
  const float* Wv    = (const float*)d_in[17];
  float* out = (float*)d_out;
  char* ws = (char*)d_ws;
  unsigned short* q_ws  = (unsigned short*)(ws + 0);          // 11.2 MB
  unsigned short* k_ws  = (unsigned short*)(ws + 11200000);   // 11.2 MB
  unsigned short* v_ws  = (unsigned short*)(ws + 22400000);   // 11.2 MB
  float* alpha_ws       = (float*)(ws + 33600000);            // 11.2 MB
  int* rs               = (int*)(ws + 44800000);              // 100,004 B
  unsigned short* W1sw  = (unsigned short*)(ws + 44900016);   // 28,672 B
  unsigned short* W2sw  = (unsigned short*)(ws + 44928688);   // 100,352 B

  k_pre<<<dim3(NBNODE + 1563 + 3), dim3(256), 0, stream>>>(
      x, Wq, Wk, Wv, idx_i, W1r, W1s, b1r, b1s, W2r, W2s,
      q_ws, k_ws, v_ws, rs, W1sw, W2sw);
  k_edge<<<dim3(1024), dim3(256), 0, stream>>>(
      rbf, cut, ev, idx_i, idx_j, W1sw, W2sw, b1r, b2r, b2s,
      q_ws, k_ws, alpha_ws);
  k_agg<<<dim3(6250), dim3(256), 0, stream>>>(
      alpha_ws, v_ws, ylm, idx_j, rs, out);
}

// Round 13
// 438.424 us; speedup vs baseline: 2.8994x; 1.0641x over previous
//
#include <hip/hip_runtime.h>
#include <hip/hip_bf16.h>

// Problem constants (from reference)
#define NNODE 25000
#define PEDGE 400000
#define FDIM  224      // F = TF = 224; q/k: 7 heads x 32, v: 4 heads x 56
#define NORD  15
#define NXOUT (NNODE*FDIM)
#define NTILE 3125     // PEDGE/128 (exact)

typedef __bf16 bf16x8 __attribute__((ext_vector_type(8)));
typedef short  s16x8  __attribute__((ext_vector_type(8)));
typedef float  f32x4  __attribute__((ext_vector_type(4)));
typedef unsigned short u16x8 __attribute__((ext_vector_type(8)));

// MFMA wrapper: tolerate either v8bf16 or v8i16 builtin signature across ROCm versions.
template <typename V>
__device__ __forceinline__ auto mfma_impl(V a, V b, f32x4 c, int)
    -> decltype(__builtin_amdgcn_mfma_f32_16x16x32_bf16(a, b, c, 0, 0, 0)) {
  return __builtin_amdgcn_mfma_f32_16x16x32_bf16(a, b, c, 0, 0, 0);
}
template <typename V>
__device__ __forceinline__ f32x4 mfma_impl(V a, V b, f32x4 c, long) {
  return __builtin_amdgcn_mfma_f32_16x16x32_bf16(
      __builtin_bit_cast(s16x8, a), __builtin_bit_cast(s16x8, b), c, 0, 0, 0);
}
__device__ __forceinline__ f32x4 MFMA_BF16(bf16x8 a, bf16x8 b, f32x4 c) {
  return mfma_impl(a, b, c, 0);
}

__device__ __forceinline__ float siluf(float x) { return x / (1.0f + __expf(-x)); }
__device__ __forceinline__ unsigned short f2bf(float x) {
  __hip_bfloat16 h = __float2bfloat16(x);
  return __builtin_bit_cast(unsigned short, h);
}
__device__ __forceinline__ float bf2f(unsigned short u) {
  unsigned int v = ((unsigned int)u) << 16;
  return __builtin_bit_cast(float, v);
}

// DPP add on the VALU pipe.
template <int CTRL>
__device__ __forceinline__ float dpp_radd(float v) {
  int s = __builtin_amdgcn_update_dpp(0, __builtin_bit_cast(int, v), CTRL, 0xf, 0xf, true);
  return v + __builtin_bit_cast(float, s);
}

// ---------------------------------------------------------------------------
// k_pre: (a) node q,k,v projections; (b) CSR row_start; (c) W1cat swizzle;
//        (d) W2cat swizzle.
//
// R16: NPB 8 -> 40. Each node-block loads the same 107 KB of Wq/Wk/Wv into
// registers; at NPB=8 that is 3125 redundant reloads (~21M dwordx4 issues,
// load-issue/waitcnt bound ~130us by issue-rate arithmetic, L2-resident so
// not BW). NPB=40 -> 625 blocks: issue count /5. xs = 40x224x4 = 35,840 B
// (4 blocks/CU). m-loop unroll capped at 2 (full 40x unroll = ~38KB I-cache
// overflow; 2 gives 6 independent FMA chains, plenty of ILP).
// ---------------------------------------------------------------------------
#define NPB 40
#define NBNODE 625   // 25000/40
__global__ __launch_bounds__(256) void k_pre(
    const float* __restrict__ x, const float* __restrict__ Wq,
    const float* __restrict__ Wk, const float* __restrict__ Wv,
    const int* __restrict__ idx_i,
    const float* __restrict__ W1r, const float* __restrict__ W1s,
    const float* __restrict__ b1r, const float* __restrict__ b1s,
    const float* __restrict__ W2r, const float* __restrict__ W2s,
    unsigned short* __restrict__ q_ws, unsigned short* __restrict__ k_ws,
    unsigned short* __restrict__ v_ws, int* __restrict__ rs,
    unsigned short* __restrict__ W1sw, unsigned short* __restrict__ W2sw) {
  int b = blockIdx.x, t = threadIdx.x;
  if (b < NBNODE) {
    __shared__ float xs[NPB * FDIM];           // 35,840 B
    int n0 = b * NPB;
    const float4* x4 = (const float4*)(x + n0 * FDIM);
    float4* xs4 = (float4*)xs;
    for (int i = t; i < NPB * (FDIM/4); i += 256) xs4[i] = x4[i];
    float wq[32], wk[32], wv[56];
    int h = 0, d = 0;
    if (t < FDIM) {
      #pragma unroll
      for (int j = 0; j < 32; j++) { wq[j] = Wq[t*32 + j]; wk[j] = Wk[t*32 + j]; }
      h = t / 56; d = t - h*56;
      #pragma unroll
      for (int j = 0; j < 56; j++) wv[j] = Wv[(h*56 + d)*56 + j];
    }
    __syncthreads();
    if (t < FDIM) {
      int qh = t >> 5;
      #pragma unroll 2
      for (int m = 0; m < NPB; m++) {
        const float* xr = xs + m*FDIM;
        const float* xh = xr + (qh << 5);
        float aq = 0.f, ak = 0.f;
        #pragma unroll
        for (int j = 0; j < 32; j++) { aq += wq[j]*xh[j]; ak += wk[j]*xh[j]; }
        int n = n0 + m;
        q_ws[n*FDIM + t] = f2bf(siluf(aq));
        k_ws[n*FDIM + t] = f2bf(siluf(ak));
        const float* xv = xr + h*56;
        float av = 0.f;
        #pragma unroll
        for (int j = 0; j < 56; j++) av += wv[j]*xv[j];
        v_ws[n*FDIM + t] = f2bf(av);   // no silu on v
      }
    }
  } else if (b < NBNODE + 1563) {
    int p = (b - NBNODE)*256 + t;
    if (p < PEDGE) {
      int cur = idx_i[p];
      if (p == 0) { for (int v = 0; v <= cur; v++) rs[v] = 0; }
      else { int prev = idx_i[p-1]; for (int v = prev+1; v <= cur; v++) rs[v] = p; }
      if (p == PEDGE-1) { for (int v = cur+1; v <= NNODE; v++) rs[v] = PEDGE; }
    }
  } else if (b == NBNODE + 1563) {
    // W1cat[row<64][col<224]; row 35 = b1cat (bias folded into GEMM)
    for (int lin = t; lin < 64*224; lin += 256) {
      int row = lin / 224, col = lin - row*224;
      float v = 0.f;
      if (row < 32) { if (col < 112) v = W1r[row*112 + col]; }
      else if (row < 35) { if (col >= 112) v = W1s[(row-32)*112 + (col-112)]; }
      else if (row == 35) v = (col < 112) ? b1r[col] : b1s[col-112];
      int nt = col >> 4, lanelo = col & 15, k = row >> 5, hi = (row >> 3) & 3, j = row & 7;
      W1sw[(((nt*2 + k)*64) + hi*16 + lanelo)*8 + j] = f2bf(v);
    }
  } else {
    // W2cat (224x224) -> swizzled global, output-linear (coalesced writes)
    int half = b - (NBNODE + 1564);      // 0 or 1
    int o0 = half * 25088;
    for (int o = o0 + t; o < o0 + 25088; o += 256) {
      int j = o & 7, lane = (o >> 3) & 63, rest = o >> 9;
      int hi = lane >> 4, lanelo = lane & 15;
      int k32 = rest % 7, nt = rest / 7;
      int row = k32*32 + hi*8 + j, col = nt*16 + lanelo;
      float v = (row < 112) ? W2r[row*224 + col] : W2s[(row-112)*224 + col];
      W2sw[o] = f2bf(v);
    }
  }
}

// ---------------------------------------------------------------------------
// k_edge R15 (FROZEN this round) = R9 structure + block-diagonal layer-1.
// Measured: 198 us, occ 40%, FETCH ~259 MB, WRITE ~136 MB (aa spill
// accepted — all 5 restructures to remove it regressed: R10/R11/R12/R14).
// ---------------------------------------------------------------------------
#define HSTRIDE 136
#define WSTRIDE 36
__global__ __launch_bounds__(256, 4) void k_edge(
    const float* __restrict__ rbf, const float* __restrict__ cut,
    const float* __restrict__ ev,
    const int* __restrict__ idx_i, const int* __restrict__ idx_j,
    const unsigned short* __restrict__ W1sw,
    const unsigned short* __restrict__ W2sw,
    const float* __restrict__ b1r,
    const float* __restrict__ b2r, const float* __restrict__ b2s,
    const unsigned short* __restrict__ q_ws, const unsigned short* __restrict__ k_ws,
    float* __restrict__ alpha_ws) {
  __shared__ __bf16 h1s[128*HSTRIDE];    // 34,816 B
  int tid = threadIdx.x;
  int wave = tid >> 6, lane = tid & 63;
  int mrow = lane & 15, quad = lane >> 4;
  int ed = lane >> 1, hh = lane & 1;
  float* wbuf = (float*)(h1s + wave*32*HSTRIDE);   // wave-private 8,704 B slice
  for (int T = blockIdx.x; T < NTILE; T += gridDim.x) {
    int base = T*128 + wave*32;
    // ---- u A-fragments: lane holds edge mrow (per mg), k-chunk quad*8+j ----
    bf16x8 u0[2], u1[2];
    #pragma unroll
    for (int mg = 0; mg < 2; mg++) {
      int e = base + mg*16 + mrow;
      float cu = cut[e];
      const float4* r4 = (const float4*)(rbf + e*32 + quad*8);
      float4 v0 = r4[0], v1 = r4[1];
      u0[mg][0] = (__bf16)(v0.x*cu); u0[mg][1] = (__bf16)(v0.y*cu);
      u0[mg][2] = (__bf16)(v0.z*cu); u0[mg][3] = (__bf16)(v0.w*cu);
      u0[mg][4] = (__bf16)(v1.x*cu); u0[mg][5] = (__bf16)(v1.y*cu);
      u0[mg][6] = (__bf16)(v1.z*cu); u0[mg][7] = (__bf16)(v1.w*cu);
      #pragma unroll
      for (int j = 0; j < 8; j++) u1[mg][j] = (__bf16)0.f;
      if (quad == 0) {   // k = 32..35: l0 contraction + bias row (k=35)
        int ie = idx_i[e], je = idx_j[e];
        const float* evi = ev + ie*NORD; const float* evj = ev + je*NORD;
        float s0 = 0.f, s1 = 0.f, s2 = 0.f;
        #pragma unroll
        for (int o = 0; o < 3; o++)  { float dd = evj[o]-evi[o]; s0 += dd*dd; }
        #pragma unroll
        for (int o = 3; o < 8; o++)  { float dd = evj[o]-evi[o]; s1 += dd*dd; }
        #pragma unroll
        for (int o = 8; o < 15; o++) { float dd = evj[o]-evi[o]; s2 += dd*dd; }
        u1[mg][0] = (__bf16)s0; u1[mg][1] = (__bf16)s1; u1[mg][2] = (__bf16)s2;
        u1[mg][3] = (__bf16)1.0f;   // bias row k=35
      }
    }
    bf16x8 aa[2][7];
    // ---- layer 1 stage A (block-diag): nt 0..6 u0-only + scalar b1r;
    //      nt 7 u1-only (bias row). cols 0..127 ----
    #pragma unroll
    for (int nt = 0; nt < 7; nt++) {
      bf16x8 b0 = *(const bf16x8*)(W1sw + ((nt*2 + 0)*64 + lane)*8);
      float bv1 = b1r[nt*16 + mrow];
      int colg = nt*16 + mrow;
      #pragma unroll
      for (int mg = 0; mg < 2; mg++) {
        f32x4 acc = {bv1, bv1, bv1, bv1};
        acc = MFMA_BF16(u0[mg], b0, acc);
        int rowb = wave*32 + mg*16 + quad*4;
        #pragma unroll
        for (int r = 0; r < 4; r++)
          h1s[(rowb + r)*HSTRIDE + colg] = (__bf16)siluf(acc[r]);
      }
    }
    {
      int nt = 7;
      bf16x8 b1 = *(const bf16x8*)(W1sw + ((nt*2 + 1)*64 + lane)*8);
      int colg = nt*16 + mrow;
      #pragma unroll
      for (int mg = 0; mg < 2; mg++) {
        f32x4 acc = {0.f, 0.f, 0.f, 0.f};
        acc = MFMA_BF16(u1[mg], b1, acc);
        int rowb = wave*32 + mg*16 + quad*4;
        #pragma unroll
        for (int r = 0; r < 4; r++)
          h1s[(rowb + r)*HSTRIDE + colg] = (__bf16)siluf(acc[r]);
      }
    }
    // ---- aa[*][0..3] (same-wave RAW through LDS; lgkmcnt orders) ----
    #pragma unroll
    for (int mg = 0; mg < 2; mg++) {
      int rowa = wave*32 + mg*16 + mrow;
      #pragma unroll
      for (int kt = 0; kt < 4; kt++)
        aa[mg][kt] = *(const bf16x8*)&h1s[rowa*HSTRIDE + kt*32 + quad*8];
    }
    // ---- layer 1 stage B (block-diag): nt 8..13 u1-only -> cols 0..95
    //      (buffer reuse; WAR ordered by same-wave in-order LDS pipe) ----
    #pragma unroll
    for (int nt = 8; nt < 14; nt++) {
      bf16x8 b1 = *(const bf16x8*)(W1sw + ((nt*2 + 1)*64 + lane)*8);
      int colg = (nt-8)*16 + mrow;
      #pragma unroll
      for (int mg = 0; mg < 2; mg++) {
        f32x4 acc = {0.f, 0.f, 0.f, 0.f};
        acc = MFMA_BF16(u1[mg], b1, acc);
        int rowb = wave*32 + mg*16 + quad*4;
        #pragma unroll
        for (int r = 0; r < 4; r++)
          h1s[(rowb + r)*HSTRIDE + colg] = (__bf16)siluf(acc[r]);
      }
    }
    // ---- aa[*][4..6] ----
    #pragma unroll
    for (int mg = 0; mg < 2; mg++) {
      int rowa = wave*32 + mg*16 + mrow;
      #pragma unroll
      for (int kt = 4; kt < 7; kt++)
        aa[mg][kt] = *(const bf16x8*)&h1s[rowa*HSTRIDE + (kt-4)*32 + quad*8];
    }
    // fence: h1s (bf16) is about to be reused as f32 wbuf (TBAA boundary)
    asm volatile("" ::: "memory");
    // ---- owned-edge metadata for consumer phase ----
    int eo = base + ed;
    int io = idx_i[eo], jo = idx_j[eo];
    float co = cut[eo];
    const unsigned short* qrow = q_ws + io*FDIM + hh*16;
    const unsigned short* krow = k_ws + jo*FDIM + hh*16;
    // ---- layer 2 + alpha: per 32-col chunk h, MFMA -> wbuf -> per-edge dot
    #pragma unroll 1
    for (int h = 0; h < 7; h++) {
      // producer: w chunk (rows 0..31 = this wave's edges, cols 0..31)
      #pragma unroll
      for (int t2 = 0; t2 < 2; t2++) {
        int nt = h*2 + t2;
        int colg = nt*16 + mrow;
        float bv = b2r[colg] + b2s[colg];   // L1-resident
        f32x4 acc0 = {bv, bv, bv, bv}, acc1 = {bv, bv, bv, bv};
        #pragma unroll
        for (int kt = 0; kt < 7; kt++) {
          bf16x8 bb = *(const bf16x8*)(W2sw + ((nt*7 + kt)*64 + lane)*8);
          acc0 = MFMA_BF16(aa[0][kt], bb, acc0);
          acc1 = MFMA_BF16(aa[1][kt], bb, acc1);
        }
        int cw = t2*16 + mrow;
        #pragma unroll
        for (int r = 0; r < 4; r++) {
          wbuf[(quad*4 + r)*WSTRIDE + cw]      = acc0[r];
          wbuf[(16 + quad*4 + r)*WSTRIDE + cw] = acc1[r];
        }
      }
      // consumer: lane owns edge ed, cols [h*32 + hh*16, +16)
      const f32x4* wp = (const f32x4*)(wbuf + ed*WSTRIDE + hh*16);
      f32x4 w0 = wp[0], w1 = wp[1], w2 = wp[2], w3 = wp[3];
      u16x8 q0 = *(const u16x8*)(qrow + h*32);
      u16x8 q1 = *(const u16x8*)(qrow + h*32 + 8);
      u16x8 k0 = *(const u16x8*)(krow + h*32);
      u16x8 k1 = *(const u16x8*)(krow + h*32 + 8);
      float s = 0.f;
      #pragma unroll
      for (int j = 0; j < 4; j++) {
        s += w0[j] * (bf2f(q0[j])   * bf2f(k0[j]));
        s += w1[j] * (bf2f(q0[j+4]) * bf2f(k0[j+4]));
        s += w2[j] * (bf2f(q1[j])   * bf2f(k1[j]));
        s += w3[j] * (bf2f(q1[j+4]) * bf2f(k1[j+4]));
      }
      s = dpp_radd<0xB1>(s);     // pair-reduce (lane xor 1): full 32-col sum
      if (hh == 0) alpha_ws[eo*7 + h] = s * co;
    }
    // fence: next tile's bf16 h1 writes must not hoist above this tile's
    // f32 wbuf reads (same bytes, different TBAA types).
    asm volatile("" ::: "memory");
  }
}

// ---------------------------------------------------------------------------
// k_agg: one wave per node; 4-wide v loads; unrolled x2; zeros for empty segs.
// (FROZEN this round.)
// ---------------------------------------------------------------------------
__global__ __launch_bounds__(256) void k_agg(
    const float* __restrict__ alpha_ws, const unsigned short* __restrict__ v_ws,
    const float* __restrict__ ylm, const int* __restrict__ idx_j,
    const int* __restrict__ rs, float* __restrict__ out) {
  int n = blockIdx.x*4 + (threadIdx.x >> 6);
  if (n >= NNODE) return;
  int lane = threadIdx.x & 63;
  int s = rs[n], e = rs[n+1];
  if (lane < 56) {
    int c = lane*4, h = lane/14;      // 4 cols per lane, same head (56%4==0)
    float ax = 0.f, ay = 0.f, az = 0.f, aw = 0.f;
    int p = s;
    for (; p + 1 < e; p += 2) {
      int j0 = idx_j[p], j1 = idx_j[p+1];
      float a0 = alpha_ws[p*7 + h], a1 = alpha_ws[(p+1)*7 + h];
      ushort4 w0 = *(const ushort4*)(v_ws + j0*FDIM + c);
      ushort4 w1 = *(const ushort4*)(v_ws + j1*FDIM + c);
      ax += a0*bf2f(w0.x) + a1*bf2f(w1.x);
      ay += a0*bf2f(w0.y) + a1*bf2f(w1.y);
      az += a0*bf2f(w0.z) + a1*bf2f(w1.z);
      aw += a0*bf2f(w0.w) + a1*bf2f(w1.w);
    }
    if (p < e) {
      int j0 = idx_j[p];
      float a0 = alpha_ws[p*7 + h];
      ushort4 w0 = *(const ushort4*)(v_ws + j0*FDIM + c);
      ax += a0*bf2f(w0.x); ay += a0*bf2f(w0.y);
      az += a0*bf2f(w0.z); aw += a0*bf2f(w0.w);
    }
    float4 o4 = {ax, ay, az, aw};
    *(float4*)(out + n*FDIM + c) = o4;
  } else {
    int o = lane - 56;                // 0..7 ; second col o+8 (8..14)
    int dg0 = (o < 3) ? 0 : ((o < 8) ? 1 : 2);
    float a0 = 0.f, a1 = 0.f;
    for (int p = s; p < e; p++) {
      const float* ap = alpha_ws + p*7 + 4;
      a0 += ap[dg0] * ylm[p*NORD + o];
      if (o < 7) a1 += ap[2] * ylm[p*NORD + o + 8];
    }
    out[NXOUT + n*NORD + o] = a0;
    if (o < 7) out[NXOUT + n*NORD + o + 8] = a1;
  }
}

extern "C" void kernel_launch(void* const* d_in, const int* in_sizes, int n_in,
                              void* d_out, int out_size, void* d_ws, size_t ws_size,
                              hipStream_t stream) {
  const float* x     = (const float*)d_in[0];
  const float* ev    = (const float*)d_in[1];
  const float* rbf   = (const float*)d_in[2];
  const float* ylm   = (const float*)d_in[3];
  const float* cut   = (const float*)d_in[4];
  const int*   idx_i = (const int*)d_in[5];
  const int*   idx_j = (const int*)d_in[6];
  const float* W1r   = (const float*)d_in[7];
  const float* b1r   = (const float*)d_in[8];
  const float* W2r   = (const float*)d_in[9];
  const float* b2r   = (const float*)d_in[10];
  const float* W1s   = (const float*)d_in[11];
  const float* b1s   = (const float*)d_in[12];
  const float* W2s   = (const float*)d_in[13];
  const float* b2s   = (const float*)d_in[14];
  const float* Wq    = (const float*)d_in[15];
  const float* Wk    = (const float*)d_in[16];
  const float* Wv    = (const float*)d_in[17];
  float* out = (float*)d_out;
  char* ws = (char*)d_ws;
  unsigned short* q_ws  = (unsigned short*)(ws + 0);          // 11.2 MB
  unsigned short* k_ws  = (unsigned short*)(ws + 11200000);   // 11.2 MB
  unsigned short* v_ws  = (unsigned short*)(ws + 22400000);   // 11.2 MB
  float* alpha_ws       = (float*)(ws + 33600000);            // 11.2 MB
  int* rs               = (int*)(ws + 44800000);              // 100,004 B
  unsigned short* W1sw  = (unsigned short*)(ws + 44900016);   // 28,672 B
  unsigned short* W2sw  = (unsigned short*)(ws + 44928688);   // 100,352 B

  k_pre<<<dim3(NBNODE + 1563 + 3), dim3(256), 0, stream>>>(
      x, Wq, Wk, Wv, idx_i, W1r, W1s, b1r, b1s, W2r, W2s,
      q_ws, k_ws, v_ws, rs, W1sw, W2sw);
  k_edge<<<dim3(1024), dim3(256), 0, stream>>>(
      rbf, cut, ev, idx_i, idx_j, W1sw, W2sw, b1r, b2r, b2s,
      q_ws, k_ws, alpha_ws);
  k_agg<<<dim3(6250), dim3(256), 0, stream>>>(
      alpha_ws, v_ws, ylm, idx_j, rs, out);
}

// Round 14
// 432.172 us; speedup vs baseline: 2.9413x; 1.0145x over previous
//
#include <hip/hip_runtime.h>
#include <hip/hip_bf16.h>

// Problem constants (from reference)
#define NNODE 25000
#define PEDGE 400000
#define FDIM  224      // F = TF = 224; q/k: 7 heads x 32, v: 4 heads x 56
#define NORD  15
#define NXOUT (NNODE*FDIM)
#define NTILE 3125     // PEDGE/128 (exact)

typedef __bf16 bf16x8 __attribute__((ext_vector_type(8)));
typedef short  s16x8  __attribute__((ext_vector_type(8)));
typedef float  f32x4  __attribute__((ext_vector_type(4)));
typedef unsigned short u16x8 __attribute__((ext_vector_type(8)));

// MFMA wrapper: tolerate either v8bf16 or v8i16 builtin signature across ROCm versions.
template <typename V>
__device__ __forceinline__ auto mfma_impl(V a, V b, f32x4 c, int)
    -> decltype(__builtin_amdgcn_mfma_f32_16x16x32_bf16(a, b, c, 0, 0, 0)) {
  return __builtin_amdgcn_mfma_f32_16x16x32_bf16(a, b, c, 0, 0, 0);
}
template <typename V>
__device__ __forceinline__ f32x4 mfma_impl(V a, V b, f32x4 c, long) {
  return __builtin_amdgcn_mfma_f32_16x16x32_bf16(
      __builtin_bit_cast(s16x8, a), __builtin_bit_cast(s16x8, b), c, 0, 0, 0);
}
__device__ __forceinline__ f32x4 MFMA_BF16(bf16x8 a, bf16x8 b, f32x4 c) {
  return mfma_impl(a, b, c, 0);
}

__device__ __forceinline__ float siluf(float x) { return x / (1.0f + __expf(-x)); }
__device__ __forceinline__ unsigned short f2bf(float x) {
  __hip_bfloat16 h = __float2bfloat16(x);
  return __builtin_bit_cast(unsigned short, h);
}
__device__ __forceinline__ float bf2f(unsigned short u) {
  unsigned int v = ((unsigned int)u) << 16;
  return __builtin_bit_cast(float, v);
}

// DPP add on the VALU pipe.
template <int CTRL>
__device__ __forceinline__ float dpp_radd(float v) {
  int s = __builtin_amdgcn_update_dpp(0, __builtin_bit_cast(int, v), CTRL, 0xf, 0xf, true);
  return v + __builtin_bit_cast(float, s);
}

// ---------------------------------------------------------------------------
// k_pre (FROZEN this round, R16 state): NPB=40, 625 node-blocks. Verified
// -28 us total vs NPB=8 (weight-reload issue bound).
// ---------------------------------------------------------------------------
#define NPB 40
#define NBNODE 625   // 25000/40
__global__ __launch_bounds__(256) void k_pre(
    const float* __restrict__ x, const float* __restrict__ Wq,
    const float* __restrict__ Wk, const float* __restrict__ Wv,
    const int* __restrict__ idx_i,
    const float* __restrict__ W1r, const float* __restrict__ W1s,
    const float* __restrict__ b1r, const float* __restrict__ b1s,
    const float* __restrict__ W2r, const float* __restrict__ W2s,
    unsigned short* __restrict__ q_ws, unsigned short* __restrict__ k_ws,
    unsigned short* __restrict__ v_ws, int* __restrict__ rs,
    unsigned short* __restrict__ W1sw, unsigned short* __restrict__ W2sw) {
  int b = blockIdx.x, t = threadIdx.x;
  if (b < NBNODE) {
    __shared__ float xs[NPB * FDIM];           // 35,840 B
    int n0 = b * NPB;
    const float4* x4 = (const float4*)(x + n0 * FDIM);
    float4* xs4 = (float4*)xs;
    for (int i = t; i < NPB * (FDIM/4); i += 256) xs4[i] = x4[i];
    float wq[32], wk[32], wv[56];
    int h = 0, d = 0;
    if (t < FDIM) {
      #pragma unroll
      for (int j = 0; j < 32; j++) { wq[j] = Wq[t*32 + j]; wk[j] = Wk[t*32 + j]; }
      h = t / 56; d = t - h*56;
      #pragma unroll
      for (int j = 0; j < 56; j++) wv[j] = Wv[(h*56 + d)*56 + j];
    }
    __syncthreads();
    if (t < FDIM) {
      int qh = t >> 5;
      #pragma unroll 2
      for (int m = 0; m < NPB; m++) {
        const float* xr = xs + m*FDIM;
        const float* xh = xr + (qh << 5);
        float aq = 0.f, ak = 0.f;
        #pragma unroll
        for (int j = 0; j < 32; j++) { aq += wq[j]*xh[j]; ak += wk[j]*xh[j]; }
        int n = n0 + m;
        q_ws[n*FDIM + t] = f2bf(siluf(aq));
        k_ws[n*FDIM + t] = f2bf(siluf(ak));
        const float* xv = xr + h*56;
        float av = 0.f;
        #pragma unroll
        for (int j = 0; j < 56; j++) av += wv[j]*xv[j];
        v_ws[n*FDIM + t] = f2bf(av);   // no silu on v
      }
    }
  } else if (b < NBNODE + 1563) {
    int p = (b - NBNODE)*256 + t;
    if (p < PEDGE) {
      int cur = idx_i[p];
      if (p == 0) { for (int v = 0; v <= cur; v++) rs[v] = 0; }
      else { int prev = idx_i[p-1]; for (int v = prev+1; v <= cur; v++) rs[v] = p; }
      if (p == PEDGE-1) { for (int v = cur+1; v <= NNODE; v++) rs[v] = PEDGE; }
    }
  } else if (b == NBNODE + 1563) {
    // W1cat[row<64][col<224]; row 35 = b1cat (bias folded into GEMM)
    for (int lin = t; lin < 64*224; lin += 256) {
      int row = lin / 224, col = lin - row*224;
      float v = 0.f;
      if (row < 32) { if (col < 112) v = W1r[row*112 + col]; }
      else if (row < 35) { if (col >= 112) v = W1s[(row-32)*112 + (col-112)]; }
      else if (row == 35) v = (col < 112) ? b1r[col] : b1s[col-112];
      int nt = col >> 4, lanelo = col & 15, k = row >> 5, hi = (row >> 3) & 3, j = row & 7;
      W1sw[(((nt*2 + k)*64) + hi*16 + lanelo)*8 + j] = f2bf(v);
    }
  } else {
    // W2cat (224x224) -> swizzled global, output-linear (coalesced writes)
    int half = b - (NBNODE + 1564);      // 0 or 1
    int o0 = half * 25088;
    for (int o = o0 + t; o < o0 + 25088; o += 256) {
      int j = o & 7, lane = (o >> 3) & 63, rest = o >> 9;
      int hi = lane >> 4, lanelo = lane & 15;
      int k32 = rest % 7, nt = rest / 7;
      int row = k32*32 + hi*8 + j, col = nt*16 + lanelo;
      float v = (row < 112) ? W2r[row*224 + col] : W2s[(row-112)*224 + col];
      W2sw[o] = f2bf(v);
    }
  }
}

// ---------------------------------------------------------------------------
// k_edge (FROZEN, R15 state) = R9 structure + block-diagonal layer-1.
// Measured: 198 us, occ 40%, FETCH ~258 MB, WRITE ~135 MB (aa spill
// accepted — all 5 restructures to remove it regressed: R10/R11/R12/R14).
// ---------------------------------------------------------------------------
#define HSTRIDE 136
#define WSTRIDE 36
__global__ __launch_bounds__(256, 4) void k_edge(
    const float* __restrict__ rbf, const float* __restrict__ cut,
    const float* __restrict__ ev,
    const int* __restrict__ idx_i, const int* __restrict__ idx_j,
    const unsigned short* __restrict__ W1sw,
    const unsigned short* __restrict__ W2sw,
    const float* __restrict__ b1r,
    const float* __restrict__ b2r, const float* __restrict__ b2s,
    const unsigned short* __restrict__ q_ws, const unsigned short* __restrict__ k_ws,
    float* __restrict__ alpha_ws) {
  __shared__ __bf16 h1s[128*HSTRIDE];    // 34,816 B
  int tid = threadIdx.x;
  int wave = tid >> 6, lane = tid & 63;
  int mrow = lane & 15, quad = lane >> 4;
  int ed = lane >> 1, hh = lane & 1;
  float* wbuf = (float*)(h1s + wave*32*HSTRIDE);   // wave-private 8,704 B slice
  for (int T = blockIdx.x; T < NTILE; T += gridDim.x) {
    int base = T*128 + wave*32;
    // ---- u A-fragments: lane holds edge mrow (per mg), k-chunk quad*8+j ----
    bf16x8 u0[2], u1[2];
    #pragma unroll
    for (int mg = 0; mg < 2; mg++) {
      int e = base + mg*16 + mrow;
      float cu = cut[e];
      const float4* r4 = (const float4*)(rbf + e*32 + quad*8);
      float4 v0 = r4[0], v1 = r4[1];
      u0[mg][0] = (__bf16)(v0.x*cu); u0[mg][1] = (__bf16)(v0.y*cu);
      u0[mg][2] = (__bf16)(v0.z*cu); u0[mg][3] = (__bf16)(v0.w*cu);
      u0[mg][4] = (__bf16)(v1.x*cu); u0[mg][5] = (__bf16)(v1.y*cu);
      u0[mg][6] = (__bf16)(v1.z*cu); u0[mg][7] = (__bf16)(v1.w*cu);
      #pragma unroll
      for (int j = 0; j < 8; j++) u1[mg][j] = (__bf16)0.f;
      if (quad == 0) {   // k = 32..35: l0 contraction + bias row (k=35)
        int ie = idx_i[e], je = idx_j[e];
        const float* evi = ev + ie*NORD; const float* evj = ev + je*NORD;
        float s0 = 0.f, s1 = 0.f, s2 = 0.f;
        #pragma unroll
        for (int o = 0; o < 3; o++)  { float dd = evj[o]-evi[o]; s0 += dd*dd; }
        #pragma unroll
        for (int o = 3; o < 8; o++)  { float dd = evj[o]-evi[o]; s1 += dd*dd; }
        #pragma unroll
        for (int o = 8; o < 15; o++) { float dd = evj[o]-evi[o]; s2 += dd*dd; }
        u1[mg][0] = (__bf16)s0; u1[mg][1] = (__bf16)s1; u1[mg][2] = (__bf16)s2;
        u1[mg][3] = (__bf16)1.0f;   // bias row k=35
      }
    }
    bf16x8 aa[2][7];
    // ---- layer 1 stage A (block-diag): nt 0..6 u0-only + scalar b1r;
    //      nt 7 u1-only (bias row). cols 0..127 ----
    #pragma unroll
    for (int nt = 0; nt < 7; nt++) {
      bf16x8 b0 = *(const bf16x8*)(W1sw + ((nt*2 + 0)*64 + lane)*8);
      float bv1 = b1r[nt*16 + mrow];
      int colg = nt*16 + mrow;
      #pragma unroll
      for (int mg = 0; mg < 2; mg++) {
        f32x4 acc = {bv1, bv1, bv1, bv1};
        acc = MFMA_BF16(u0[mg], b0, acc);
        int rowb = wave*32 + mg*16 + quad*4;
        #pragma unroll
        for (int r = 0; r < 4; r++)
          h1s[(rowb + r)*HSTRIDE + colg] = (__bf16)siluf(acc[r]);
      }
    }
    {
      int nt = 7;
      bf16x8 b1 = *(const bf16x8*)(W1sw + ((nt*2 + 1)*64 + lane)*8);
      int colg = nt*16 + mrow;
      #pragma unroll
      for (int mg = 0; mg < 2; mg++) {
        f32x4 acc = {0.f, 0.f, 0.f, 0.f};
        acc = MFMA_BF16(u1[mg], b1, acc);
        int rowb = wave*32 + mg*16 + quad*4;
        #pragma unroll
        for (int r = 0; r < 4; r++)
          h1s[(rowb + r)*HSTRIDE + colg] = (__bf16)siluf(acc[r]);
      }
    }
    // ---- aa[*][0..3] (same-wave RAW through LDS; lgkmcnt orders) ----
    #pragma unroll
    for (int mg = 0; mg < 2; mg++) {
      int rowa = wave*32 + mg*16 + mrow;
      #pragma unroll
      for (int kt = 0; kt < 4; kt++)
        aa[mg][kt] = *(const bf16x8*)&h1s[rowa*HSTRIDE + kt*32 + quad*8];
    }
    // ---- layer 1 stage B (block-diag): nt 8..13 u1-only -> cols 0..95
    //      (buffer reuse; WAR ordered by same-wave in-order LDS pipe) ----
    #pragma unroll
    for (int nt = 8; nt < 14; nt++) {
      bf16x8 b1 = *(const bf16x8*)(W1sw + ((nt*2 + 1)*64 + lane)*8);
      int colg = (nt-8)*16 + mrow;
      #pragma unroll
      for (int mg = 0; mg < 2; mg++) {
        f32x4 acc = {0.f, 0.f, 0.f, 0.f};
        acc = MFMA_BF16(u1[mg], b1, acc);
        int rowb = wave*32 + mg*16 + quad*4;
        #pragma unroll
        for (int r = 0; r < 4; r++)
          h1s[(rowb + r)*HSTRIDE + colg] = (__bf16)siluf(acc[r]);
      }
    }
    // ---- aa[*][4..6] ----
    #pragma unroll
    for (int mg = 0; mg < 2; mg++) {
      int rowa = wave*32 + mg*16 + mrow;
      #pragma unroll
      for (int kt = 4; kt < 7; kt++)
        aa[mg][kt] = *(const bf16x8*)&h1s[rowa*HSTRIDE + (kt-4)*32 + quad*8];
    }
    // fence: h1s (bf16) is about to be reused as f32 wbuf (TBAA boundary)
    asm volatile("" ::: "memory");
    // ---- owned-edge metadata for consumer phase ----
    int eo = base + ed;
    int io = idx_i[eo], jo = idx_j[eo];
    float co = cut[eo];
    const unsigned short* qrow = q_ws + io*FDIM + hh*16;
    const unsigned short* krow = k_ws + jo*FDIM + hh*16;
    // ---- layer 2 + alpha: per 32-col chunk h, MFMA -> wbuf -> per-edge dot
    #pragma unroll 1
    for (int h = 0; h < 7; h++) {
      // producer: w chunk (rows 0..31 = this wave's edges, cols 0..31)
      #pragma unroll
      for (int t2 = 0; t2 < 2; t2++) {
        int nt = h*2 + t2;
        int colg = nt*16 + mrow;
        float bv = b2r[colg] + b2s[colg];   // L1-resident
        f32x4 acc0 = {bv, bv, bv, bv}, acc1 = {bv, bv, bv, bv};
        #pragma unroll
        for (int kt = 0; kt < 7; kt++) {
          bf16x8 bb = *(const bf16x8*)(W2sw + ((nt*7 + kt)*64 + lane)*8);
          acc0 = MFMA_BF16(aa[0][kt], bb, acc0);
          acc1 = MFMA_BF16(aa[1][kt], bb, acc1);
        }
        int cw = t2*16 + mrow;
        #pragma unroll
        for (int r = 0; r < 4; r++) {
          wbuf[(quad*4 + r)*WSTRIDE + cw]      = acc0[r];
          wbuf[(16 + quad*4 + r)*WSTRIDE + cw] = acc1[r];
        }
      }
      // consumer: lane owns edge ed, cols [h*32 + hh*16, +16)
      const f32x4* wp = (const f32x4*)(wbuf + ed*WSTRIDE + hh*16);
      f32x4 w0 = wp[0], w1 = wp[1], w2 = wp[2], w3 = wp[3];
      u16x8 q0 = *(const u16x8*)(qrow + h*32);
      u16x8 q1 = *(const u16x8*)(qrow + h*32 + 8);
      u16x8 k0 = *(const u16x8*)(krow + h*32);
      u16x8 k1 = *(const u16x8*)(krow + h*32 + 8);
      float s = 0.f;
      #pragma unroll
      for (int j = 0; j < 4; j++) {
        s += w0[j] * (bf2f(q0[j])   * bf2f(k0[j]));
        s += w1[j] * (bf2f(q0[j+4]) * bf2f(k0[j+4]));
        s += w2[j] * (bf2f(q1[j])   * bf2f(k1[j]));
        s += w3[j] * (bf2f(q1[j+4]) * bf2f(k1[j+4]));
      }
      s = dpp_radd<0xB1>(s);     // pair-reduce (lane xor 1): full 32-col sum
      if (hh == 0) alpha_ws[eo*7 + h] = s * co;
    }
    // fence: next tile's bf16 h1 writes must not hoist above this tile's
    // f32 wbuf reads (same bytes, different TBAA types).
    asm volatile("" ::: "memory");
  }
}

// ---------------------------------------------------------------------------
// k_agg R17: 4-deep gather unroll. Theory: v_ws (11.2 MB) overflows the
// 4 MB/XCD L2, so random v-row gathers are L3-latency-bound (~450 cy); the
// old 2-deep loop holds only 2 chains in flight per lane. 4 independent
// idx_j/alpha/v chains per iteration quadruple memory-level parallelism.
// ylm lanes (56..63) untouched. If Δtotal ≈ 0, k_agg is at its BW/issue
// floor -> next target is k_pre.
// ---------------------------------------------------------------------------
__global__ __launch_bounds__(256) void k_agg(
    const float* __restrict__ alpha_ws, const unsigned short* __restrict__ v_ws,
    const float* __restrict__ ylm, const int* __restrict__ idx_j,
    const int* __restrict__ rs, float* __restrict__ out) {
  int n = blockIdx.x*4 + (threadIdx.x >> 6);
  if (n >= NNODE) return;
  int lane = threadIdx.x & 63;
  int s = rs[n], e = rs[n+1];
  if (lane < 56) {
    int c = lane*4, h = lane/14;      // 4 cols per lane, same head (56%4==0)
    float ax = 0.f, ay = 0.f, az = 0.f, aw = 0.f;
    int p = s;
    for (; p + 3 < e; p += 4) {
      int j0 = idx_j[p],   j1 = idx_j[p+1];
      int j2 = idx_j[p+2], j3 = idx_j[p+3];
      float a0 = alpha_ws[p*7 + h],     a1 = alpha_ws[(p+1)*7 + h];
      float a2 = alpha_ws[(p+2)*7 + h], a3 = alpha_ws[(p+3)*7 + h];
      ushort4 w0 = *(const ushort4*)(v_ws + j0*FDIM + c);
      ushort4 w1 = *(const ushort4*)(v_ws + j1*FDIM + c);
      ushort4 w2 = *(const ushort4*)(v_ws + j2*FDIM + c);
      ushort4 w3 = *(const ushort4*)(v_ws + j3*FDIM + c);
      ax += a0*bf2f(w0.x) + a1*bf2f(w1.x) + a2*bf2f(w2.x) + a3*bf2f(w3.x);
      ay += a0*bf2f(w0.y) + a1*bf2f(w1.y) + a2*bf2f(w2.y) + a3*bf2f(w3.y);
      az += a0*bf2f(w0.z) + a1*bf2f(w1.z) + a2*bf2f(w2.z) + a3*bf2f(w3.z);
      aw += a0*bf2f(w0.w) + a1*bf2f(w1.w) + a2*bf2f(w2.w) + a3*bf2f(w3.w);
    }
    for (; p < e; p++) {
      int j0 = idx_j[p];
      float a0 = alpha_ws[p*7 + h];
      ushort4 w0 = *(const ushort4*)(v_ws + j0*FDIM + c);
      ax += a0*bf2f(w0.x); ay += a0*bf2f(w0.y);
      az += a0*bf2f(w0.z); aw += a0*bf2f(w0.w);
    }
    float4 o4 = {ax, ay, az, aw};
    *(float4*)(out + n*FDIM + c) = o4;
  } else {
    int o = lane - 56;                // 0..7 ; second col o+8 (8..14)
    int dg0 = (o < 3) ? 0 : ((o < 8) ? 1 : 2);
    float a0 = 0.f, a1 = 0.f;
    for (int p = s; p < e; p++) {
      const float* ap = alpha_ws + p*7 + 4;
      a0 += ap[dg0] * ylm[p*NORD + o];
      if (o < 7) a1 += ap[2] * ylm[p*NORD + o + 8];
    }
    out[NXOUT + n*NORD + o] = a0;
    if (o < 7) out[NXOUT + n*NORD + o + 8] = a1;
  }
}

extern "C" void kernel_launch(void* const* d_in, const int* in_sizes, int n_in,
                              void* d_out, int out_size, void* d_ws, size_t ws_size,
                              hipStream_t stream) {
  const float* x     = (const float*)d_in[0];
  const float* ev    = (const float*)d_in[1];
  const float* rbf   = (const float*)d_in[2];
  const float* ylm   = (const float*)d_in[3];
  const float* cut   = (const float*)d_in[4];
  const int*   idx_i = (const int*)d_in[5];
  const int*   idx_j = (const int*)d_in[6];
  const float* W1r   = (const float*)d_in[7];
  const float* b1r   = (const float*)d_in[8];
  const float* W2r   = (const float*)d_in[9];
  const float* b2r   = (const float*)d_in[10];
  const float* W1s   = (const float*)d_in[11];
  const float* b1s   = (const float*)d_in[12];
  const float* W2s   = (const float*)d_in[13];
  const float* b2s   = (const float*)d_in[14];
  const float* Wq    = (const float*)d_in[15];
  const float* Wk    = (const float*)d_in[16];
  const float* Wv    = (const float*)d_in[17];
  float* out = (float*)d_out;
  char* ws = (char*)d_ws;
  unsigned short* q_ws  = (unsigned short*)(ws + 0);          // 11.2 MB
  unsigned short* k_ws  = (unsigned short*)(ws + 11200000);   // 11.2 MB
  unsigned short* v_ws  = (unsigned short*)(ws + 22400000);   // 11.2 MB
  float* alpha_ws       = (float*)(ws + 33600000);            // 11.2 MB
  int* rs               = (int*)(ws + 44800000);              // 100,004 B
  unsigned short* W1sw  = (unsigned short*)(ws + 44900016);   // 28,672 B
  unsigned short* W2sw  = (unsigned short*)(ws + 44928688);   // 100,352 B

  k_pre<<<dim3(NBNODE + 1563 + 3), dim3(256), 0, stream>>>(
      x, Wq, Wk, Wv, idx_i, W1r, W1s, b1r, b1s, W2r, W2s,
      q_ws, k_ws, v_ws, rs, W1sw, W2sw);
  k_edge<<<dim3(1024), dim3(256), 0, stream>>>(
      rbf, cut, ev, idx_i, idx_j, W1sw, W2sw, b1r, b2r, b2s,
      q_ws, k_ws, alpha_ws);
  k_agg<<<dim3(6250), dim3(256), 0, stream>>>(
      alpha_ws, v_ws, ylm, idx_j, rs, out);
}

// Round 15
// 418.087 us; speedup vs baseline: 3.0404x; 1.0337x over previous
//
#include <hip/hip_runtime.h>
#include <hip/hip_bf16.h>

// Problem constants (from reference)
#define NNODE 25000
#define PEDGE 400000
#define FDIM  224      // F = TF = 224; q/k: 7 heads x 32, v: 4 heads x 56
#define NORD  15
#define NXOUT (NNODE*FDIM)
#define NTILE 3125     // PEDGE/128 (exact)

typedef __bf16 bf16x8 __attribute__((ext_vector_type(8)));
typedef short  s16x8  __attribute__((ext_vector_type(8)));
typedef float  f32x4  __attribute__((ext_vector_type(4)));
typedef unsigned short u16x8 __attribute__((ext_vector_type(8)));

// MFMA wrapper: tolerate either v8bf16 or v8i16 builtin signature across ROCm versions.
template <typename V>
__device__ __forceinline__ auto mfma_impl(V a, V b, f32x4 c, int)
    -> decltype(__builtin_amdgcn_mfma_f32_16x16x32_bf16(a, b, c, 0, 0, 0)) {
  return __builtin_amdgcn_mfma_f32_16x16x32_bf16(a, b, c, 0, 0, 0);
}
template <typename V>
__device__ __forceinline__ f32x4 mfma_impl(V a, V b, f32x4 c, long) {
  return __builtin_amdgcn_mfma_f32_16x16x32_bf16(
      __builtin_bit_cast(s16x8, a), __builtin_bit_cast(s16x8, b), c, 0, 0, 0);
}
__device__ __forceinline__ f32x4 MFMA_BF16(bf16x8 a, bf16x8 b, f32x4 c) {
  return mfma_impl(a, b, c, 0);
}

__device__ __forceinline__ float siluf(float x) { return x / (1.0f + __expf(-x)); }
__device__ __forceinline__ unsigned short f2bf(float x) {
  __hip_bfloat16 h = __float2bfloat16(x);
  return __builtin_bit_cast(unsigned short, h);
}
__device__ __forceinline__ float bf2f(unsigned short u) {
  unsigned int v = ((unsigned int)u) << 16;
  return __builtin_bit_cast(float, v);
}

// DPP add on the VALU pipe.
template <int CTRL>
__device__ __forceinline__ float dpp_radd(float v) {
  int s = __builtin_amdgcn_update_dpp(0, __builtin_bit_cast(int, v), CTRL, 0xf, 0xf, true);
  return v + __builtin_bit_cast(float, s);
}

// ---------------------------------------------------------------------------
// k_pre (FROZEN, R16 state): NPB=40, 625 node-blocks. Verified -28 us total
// vs NPB=8 (weight-reload issue bound).
// ---------------------------------------------------------------------------
#define NPB 40
#define NBNODE 625   // 25000/40
__global__ __launch_bounds__(256) void k_pre(
    const float* __restrict__ x, const float* __restrict__ Wq,
    const float* __restrict__ Wk, const float* __restrict__ Wv,
    const int* __restrict__ idx_i,
    const float* __restrict__ W1r, const float* __restrict__ W1s,
    const float* __restrict__ b1r, const float* __restrict__ b1s,
    const float* __restrict__ W2r, const float* __restrict__ W2s,
    unsigned short* __restrict__ q_ws, unsigned short* __restrict__ k_ws,
    unsigned short* __restrict__ v_ws, int* __restrict__ rs,
    unsigned short* __restrict__ W1sw, unsigned short* __restrict__ W2sw) {
  int b = blockIdx.x, t = threadIdx.x;
  if (b < NBNODE) {
    __shared__ float xs[NPB * FDIM];           // 35,840 B
    int n0 = b * NPB;
    const float4* x4 = (const float4*)(x + n0 * FDIM);
    float4* xs4 = (float4*)xs;
    for (int i = t; i < NPB * (FDIM/4); i += 256) xs4[i] = x4[i];
    float wq[32], wk[32], wv[56];
    int h = 0, d = 0;
    if (t < FDIM) {
      #pragma unroll
      for (int j = 0; j < 32; j++) { wq[j] = Wq[t*32 + j]; wk[j] = Wk[t*32 + j]; }
      h = t / 56; d = t - h*56;
      #pragma unroll
      for (int j = 0; j < 56; j++) wv[j] = Wv[(h*56 + d)*56 + j];
    }
    __syncthreads();
    if (t < FDIM) {
      int qh = t >> 5;
      #pragma unroll 2
      for (int m = 0; m < NPB; m++) {
        const float* xr = xs + m*FDIM;
        const float* xh = xr + (qh << 5);
        float aq = 0.f, ak = 0.f;
        #pragma unroll
        for (int j = 0; j < 32; j++) { aq += wq[j]*xh[j]; ak += wk[j]*xh[j]; }
        int n = n0 + m;
        q_ws[n*FDIM + t] = f2bf(siluf(aq));
        k_ws[n*FDIM + t] = f2bf(siluf(ak));
        const float* xv = xr + h*56;
        float av = 0.f;
        #pragma unroll
        for (int j = 0; j < 56; j++) av += wv[j]*xv[j];
        v_ws[n*FDIM + t] = f2bf(av);   // no silu on v
      }
    }
  } else if (b < NBNODE + 1563) {
    int p = (b - NBNODE)*256 + t;
    if (p < PEDGE) {
      int cur = idx_i[p];
      if (p == 0) { for (int v = 0; v <= cur; v++) rs[v] = 0; }
      else { int prev = idx_i[p-1]; for (int v = prev+1; v <= cur; v++) rs[v] = p; }
      if (p == PEDGE-1) { for (int v = cur+1; v <= NNODE; v++) rs[v] = PEDGE; }
    }
  } else if (b == NBNODE + 1563) {
    // W1cat[row<64][col<224]; row 35 = b1cat (bias folded into GEMM)
    for (int lin = t; lin < 64*224; lin += 256) {
      int row = lin / 224, col = lin - row*224;
      float v = 0.f;
      if (row < 32) { if (col < 112) v = W1r[row*112 + col]; }
      else if (row < 35) { if (col >= 112) v = W1s[(row-32)*112 + (col-112)]; }
      else if (row == 35) v = (col < 112) ? b1r[col] : b1s[col-112];
      int nt = col >> 4, lanelo = col & 15, k = row >> 5, hi = (row >> 3) & 3, j = row & 7;
      W1sw[(((nt*2 + k)*64) + hi*16 + lanelo)*8 + j] = f2bf(v);
    }
  } else {
    // W2cat (224x224) -> swizzled global, output-linear (coalesced writes)
    int half = b - (NBNODE + 1564);      // 0 or 1
    int o0 = half * 25088;
    for (int o = o0 + t; o < o0 + 25088; o += 256) {
      int j = o & 7, lane = (o >> 3) & 63, rest = o >> 9;
      int hi = lane >> 4, lanelo = lane & 15;
      int k32 = rest % 7, nt = rest / 7;
      int row = k32*32 + hi*8 + j, col = nt*16 + lanelo;
      float v = (row < 112) ? W2r[row*224 + col] : W2s[(row-112)*224 + col];
      W2sw[o] = f2bf(v);
    }
  }
}

// ---------------------------------------------------------------------------
// k_edge (FROZEN, R15 state) = R9 structure + block-diagonal layer-1.
// Measured: 198 us, occ 40%, FETCH ~258 MB, WRITE ~135 MB (aa spill
// accepted — all 5 restructures to remove it regressed: R10/R11/R12/R14).
// ---------------------------------------------------------------------------
#define HSTRIDE 136
#define WSTRIDE 36
__global__ __launch_bounds__(256, 4) void k_edge(
    const float* __restrict__ rbf, const float* __restrict__ cut,
    const float* __restrict__ ev,
    const int* __restrict__ idx_i, const int* __restrict__ idx_j,
    const unsigned short* __restrict__ W1sw,
    const unsigned short* __restrict__ W2sw,
    const float* __restrict__ b1r,
    const float* __restrict__ b2r, const float* __restrict__ b2s,
    const unsigned short* __restrict__ q_ws, const unsigned short* __restrict__ k_ws,
    float* __restrict__ alpha_ws) {
  __shared__ __bf16 h1s[128*HSTRIDE];    // 34,816 B
  int tid = threadIdx.x;
  int wave = tid >> 6, lane = tid & 63;
  int mrow = lane & 15, quad = lane >> 4;
  int ed = lane >> 1, hh = lane & 1;
  float* wbuf = (float*)(h1s + wave*32*HSTRIDE);   // wave-private 8,704 B slice
  for (int T = blockIdx.x; T < NTILE; T += gridDim.x) {
    int base = T*128 + wave*32;
    // ---- u A-fragments: lane holds edge mrow (per mg), k-chunk quad*8+j ----
    bf16x8 u0[2], u1[2];
    #pragma unroll
    for (int mg = 0; mg < 2; mg++) {
      int e = base + mg*16 + mrow;
      float cu = cut[e];
      const float4* r4 = (const float4*)(rbf + e*32 + quad*8);
      float4 v0 = r4[0], v1 = r4[1];
      u0[mg][0] = (__bf16)(v0.x*cu); u0[mg][1] = (__bf16)(v0.y*cu);
      u0[mg][2] = (__bf16)(v0.z*cu); u0[mg][3] = (__bf16)(v0.w*cu);
      u0[mg][4] = (__bf16)(v1.x*cu); u0[mg][5] = (__bf16)(v1.y*cu);
      u0[mg][6] = (__bf16)(v1.z*cu); u0[mg][7] = (__bf16)(v1.w*cu);
      #pragma unroll
      for (int j = 0; j < 8; j++) u1[mg][j] = (__bf16)0.f;
      if (quad == 0) {   // k = 32..35: l0 contraction + bias row (k=35)
        int ie = idx_i[e], je = idx_j[e];
        const float* evi = ev + ie*NORD; const float* evj = ev + je*NORD;
        float s0 = 0.f, s1 = 0.f, s2 = 0.f;
        #pragma unroll
        for (int o = 0; o < 3; o++)  { float dd = evj[o]-evi[o]; s0 += dd*dd; }
        #pragma unroll
        for (int o = 3; o < 8; o++)  { float dd = evj[o]-evi[o]; s1 += dd*dd; }
        #pragma unroll
        for (int o = 8; o < 15; o++) { float dd = evj[o]-evi[o]; s2 += dd*dd; }
        u1[mg][0] = (__bf16)s0; u1[mg][1] = (__bf16)s1; u1[mg][2] = (__bf16)s2;
        u1[mg][3] = (__bf16)1.0f;   // bias row k=35
      }
    }
    bf16x8 aa[2][7];
    // ---- layer 1 stage A (block-diag): nt 0..6 u0-only + scalar b1r;
    //      nt 7 u1-only (bias row). cols 0..127 ----
    #pragma unroll
    for (int nt = 0; nt < 7; nt++) {
      bf16x8 b0 = *(const bf16x8*)(W1sw + ((nt*2 + 0)*64 + lane)*8);
      float bv1 = b1r[nt*16 + mrow];
      int colg = nt*16 + mrow;
      #pragma unroll
      for (int mg = 0; mg < 2; mg++) {
        f32x4 acc = {bv1, bv1, bv1, bv1};
        acc = MFMA_BF16(u0[mg], b0, acc);
        int rowb = wave*32 + mg*16 + quad*4;
        #pragma unroll
        for (int r = 0; r < 4; r++)
          h1s[(rowb + r)*HSTRIDE + colg] = (__bf16)siluf(acc[r]);
      }
    }
    {
      int nt = 7;
      bf16x8 b1 = *(const bf16x8*)(W1sw + ((nt*2 + 1)*64 + lane)*8);
      int colg = nt*16 + mrow;
      #pragma unroll
      for (int mg = 0; mg < 2; mg++) {
        f32x4 acc = {0.f, 0.f, 0.f, 0.f};
        acc = MFMA_BF16(u1[mg], b1, acc);
        int rowb = wave*32 + mg*16 + quad*4;
        #pragma unroll
        for (int r = 0; r < 4; r++)
          h1s[(rowb + r)*HSTRIDE + colg] = (__bf16)siluf(acc[r]);
      }
    }
    // ---- aa[*][0..3] (same-wave RAW through LDS; lgkmcnt orders) ----
    #pragma unroll
    for (int mg = 0; mg < 2; mg++) {
      int rowa = wave*32 + mg*16 + mrow;
      #pragma unroll
      for (int kt = 0; kt < 4; kt++)
        aa[mg][kt] = *(const bf16x8*)&h1s[rowa*HSTRIDE + kt*32 + quad*8];
    }
    // ---- layer 1 stage B (block-diag): nt 8..13 u1-only -> cols 0..95
    //      (buffer reuse; WAR ordered by same-wave in-order LDS pipe) ----
    #pragma unroll
    for (int nt = 8; nt < 14; nt++) {
      bf16x8 b1 = *(const bf16x8*)(W1sw + ((nt*2 + 1)*64 + lane)*8);
      int colg = (nt-8)*16 + mrow;
      #pragma unroll
      for (int mg = 0; mg < 2; mg++) {
        f32x4 acc = {0.f, 0.f, 0.f, 0.f};
        acc = MFMA_BF16(u1[mg], b1, acc);
        int rowb = wave*32 + mg*16 + quad*4;
        #pragma unroll
        for (int r = 0; r < 4; r++)
          h1s[(rowb + r)*HSTRIDE + colg] = (__bf16)siluf(acc[r]);
      }
    }
    // ---- aa[*][4..6] ----
    #pragma unroll
    for (int mg = 0; mg < 2; mg++) {
      int rowa = wave*32 + mg*16 + mrow;
      #pragma unroll
      for (int kt = 4; kt < 7; kt++)
        aa[mg][kt] = *(const bf16x8*)&h1s[rowa*HSTRIDE + (kt-4)*32 + quad*8];
    }
    // fence: h1s (bf16) is about to be reused as f32 wbuf (TBAA boundary)
    asm volatile("" ::: "memory");
    // ---- owned-edge metadata for consumer phase ----
    int eo = base + ed;
    int io = idx_i[eo], jo = idx_j[eo];
    float co = cut[eo];
    const unsigned short* qrow = q_ws + io*FDIM + hh*16;
    const unsigned short* krow = k_ws + jo*FDIM + hh*16;
    // ---- layer 2 + alpha: per 32-col chunk h, MFMA -> wbuf -> per-edge dot
    #pragma unroll 1
    for (int h = 0; h < 7; h++) {
      // producer: w chunk (rows 0..31 = this wave's edges, cols 0..31)
      #pragma unroll
      for (int t2 = 0; t2 < 2; t2++) {
        int nt = h*2 + t2;
        int colg = nt*16 + mrow;
        float bv = b2r[colg] + b2s[colg];   // L1-resident
        f32x4 acc0 = {bv, bv, bv, bv}, acc1 = {bv, bv, bv, bv};
        #pragma unroll
        for (int kt = 0; kt < 7; kt++) {
          bf16x8 bb = *(const bf16x8*)(W2sw + ((nt*7 + kt)*64 + lane)*8);
          acc0 = MFMA_BF16(aa[0][kt], bb, acc0);
          acc1 = MFMA_BF16(aa[1][kt], bb, acc1);
        }
        int cw = t2*16 + mrow;
        #pragma unroll
        for (int r = 0; r < 4; r++) {
          wbuf[(quad*4 + r)*WSTRIDE + cw]      = acc0[r];
          wbuf[(16 + quad*4 + r)*WSTRIDE + cw] = acc1[r];
        }
      }
      // consumer: lane owns edge ed, cols [h*32 + hh*16, +16)
      const f32x4* wp = (const f32x4*)(wbuf + ed*WSTRIDE + hh*16);
      f32x4 w0 = wp[0], w1 = wp[1], w2 = wp[2], w3 = wp[3];
      u16x8 q0 = *(const u16x8*)(qrow + h*32);
      u16x8 q1 = *(const u16x8*)(qrow + h*32 + 8);
      u16x8 k0 = *(const u16x8*)(krow + h*32);
      u16x8 k1 = *(const u16x8*)(krow + h*32 + 8);
      float s = 0.f;
      #pragma unroll
      for (int j = 0; j < 4; j++) {
        s += w0[j] * (bf2f(q0[j])   * bf2f(k0[j]));
        s += w1[j] * (bf2f(q0[j+4]) * bf2f(k0[j+4]));
        s += w2[j] * (bf2f(q1[j])   * bf2f(k1[j]));
        s += w3[j] * (bf2f(q1[j+4]) * bf2f(k1[j+4]));
      }
      s = dpp_radd<0xB1>(s);     // pair-reduce (lane xor 1): full 32-col sum
      if (hh == 0) alpha_ws[eo*7 + h] = s * co;
    }
    // fence: next tile's bf16 h1 writes must not hoist above this tile's
    // f32 wbuf reads (same bytes, different TBAA types).
    asm volatile("" ::: "memory");
  }
}

// ---------------------------------------------------------------------------
// k_agg R18: the two sections are DIVERGENT BRANCHES of one wave — the
// ylm section (lanes 56..63) runs serially AFTER the v section. R17's
// 4-deep unroll only touched the v loop; the ylm loop still walked ~16
// edges 1-deep with dependent alpha/ylm loads (~300-500 cy each, 8 lanes)
// — the wave's real serial tail, explaining R17's -6us. This round: 4-deep
// unroll of the ylm loop (4 independent alpha/ylm chains). v section and
// all other kernels byte-identical.
// ---------------------------------------------------------------------------
__global__ __launch_bounds__(256) void k_agg(
    const float* __restrict__ alpha_ws, const unsigned short* __restrict__ v_ws,
    const float* __restrict__ ylm, const int* __restrict__ idx_j,
    const int* __restrict__ rs, float* __restrict__ out) {
  int n = blockIdx.x*4 + (threadIdx.x >> 6);
  if (n >= NNODE) return;
  int lane = threadIdx.x & 63;
  int s = rs[n], e = rs[n+1];
  if (lane < 56) {
    int c = lane*4, h = lane/14;      // 4 cols per lane, same head (56%4==0)
    float ax = 0.f, ay = 0.f, az = 0.f, aw = 0.f;
    int p = s;
    for (; p + 3 < e; p += 4) {
      int j0 = idx_j[p],   j1 = idx_j[p+1];
      int j2 = idx_j[p+2], j3 = idx_j[p+3];
      float a0 = alpha_ws[p*7 + h],     a1 = alpha_ws[(p+1)*7 + h];
      float a2 = alpha_ws[(p+2)*7 + h], a3 = alpha_ws[(p+3)*7 + h];
      ushort4 w0 = *(const ushort4*)(v_ws + j0*FDIM + c);
      ushort4 w1 = *(const ushort4*)(v_ws + j1*FDIM + c);
      ushort4 w2 = *(const ushort4*)(v_ws + j2*FDIM + c);
      ushort4 w3 = *(const ushort4*)(v_ws + j3*FDIM + c);
      ax += a0*bf2f(w0.x) + a1*bf2f(w1.x) + a2*bf2f(w2.x) + a3*bf2f(w3.x);
      ay += a0*bf2f(w0.y) + a1*bf2f(w1.y) + a2*bf2f(w2.y) + a3*bf2f(w3.y);
      az += a0*bf2f(w0.z) + a1*bf2f(w1.z) + a2*bf2f(w2.z) + a3*bf2f(w3.z);
      aw += a0*bf2f(w0.w) + a1*bf2f(w1.w) + a2*bf2f(w2.w) + a3*bf2f(w3.w);
    }
    for (; p < e; p++) {
      int j0 = idx_j[p];
      float a0 = alpha_ws[p*7 + h];
      ushort4 w0 = *(const ushort4*)(v_ws + j0*FDIM + c);
      ax += a0*bf2f(w0.x); ay += a0*bf2f(w0.y);
      az += a0*bf2f(w0.z); aw += a0*bf2f(w0.w);
    }
    float4 o4 = {ax, ay, az, aw};
    *(float4*)(out + n*FDIM + c) = o4;
  } else {
    int o = lane - 56;                // 0..7 ; second col o+8 (8..14)
    int dg0 = (o < 3) ? 0 : ((o < 8) ? 1 : 2);
    float a0 = 0.f, a1 = 0.f;
    int p = s;
    for (; p + 3 < e; p += 4) {
      const float* ap0 = alpha_ws + p*7 + 4;
      const float* ap1 = alpha_ws + (p+1)*7 + 4;
      const float* ap2 = alpha_ws + (p+2)*7 + 4;
      const float* ap3 = alpha_ws + (p+3)*7 + 4;
      float y0 = ylm[p*NORD + o],     y1 = ylm[(p+1)*NORD + o];
      float y2 = ylm[(p+2)*NORD + o], y3 = ylm[(p+3)*NORD + o];
      a0 += ap0[dg0]*y0 + ap1[dg0]*y1 + ap2[dg0]*y2 + ap3[dg0]*y3;
      if (o < 7) {
        float z0 = ylm[p*NORD + o + 8],     z1 = ylm[(p+1)*NORD + o + 8];
        float z2 = ylm[(p+2)*NORD + o + 8], z3 = ylm[(p+3)*NORD + o + 8];
        a1 += ap0[2]*z0 + ap1[2]*z1 + ap2[2]*z2 + ap3[2]*z3;
      }
    }
    for (; p < e; p++) {
      const float* ap = alpha_ws + p*7 + 4;
      a0 += ap[dg0] * ylm[p*NORD + o];
      if (o < 7) a1 += ap[2] * ylm[p*NORD + o + 8];
    }
    out[NXOUT + n*NORD + o] = a0;
    if (o < 7) out[NXOUT + n*NORD + o + 8] = a1;
  }
}

extern "C" void kernel_launch(void* const* d_in, const int* in_sizes, int n_in,
                              void* d_out, int out_size, void* d_ws, size_t ws_size,
                              hipStream_t stream) {
  const float* x     = (const float*)d_in[0];
  const float* ev    = (const float*)d_in[1];
  const float* rbf   = (const float*)d_in[2];
  const float* ylm   = (const float*)d_in[3];
  const float* cut   = (const float*)d_in[4];
  const int*   idx_i = (const int*)d_in[5];
  const int*   idx_j = (const int*)d_in[6];
  const float* W1r   = (const float*)d_in[7];
  const float* b1r   = (const float*)d_in[8];
  const float* W2r   = (const float*)d_in[9];
  const float* b2r   = (const float*)d_in[10];
  const float* W1s   = (const float*)d_in[11];
  const float* b1s   = (const float*)d_in[12];
  const float* W2s   = (const float*)d_in[13];
  const float* b2s   = (const float*)d_in[14];
  const float* Wq    = (const float*)d_in[15];
  const float* Wk    = (const float*)d_in[16];
  const float* Wv    = (const float*)d_in[17];
  float* out = (float*)d_out;
  char* ws = (char*)d_ws;
  unsigned short* q_ws  = (unsigned short*)(ws + 0);          // 11.2 MB
  unsigned short* k_ws  = (unsigned short*)(ws + 11200000);   // 11.2 MB
  unsigned short* v_ws  = (unsigned short*)(ws + 22400000);   // 11.2 MB
  float* alpha_ws       = (float*)(ws + 33600000);            // 11.2 MB
  int* rs               = (int*)(ws + 44800000);              // 100,004 B
  unsigned short* W1sw  = (unsigned short*)(ws + 44900016);   // 28,672 B
  unsigned short* W2sw  = (unsigned short*)(ws + 44928688);   // 100,352 B

  k_pre<<<dim3(NBNODE + 1563 + 3), dim3(256), 0, stream>>>(
      x, Wq, Wk, Wv, idx_i, W1r, W1s, b1r, b1s, W2r, W2s,
      q_ws, k_ws, v_ws, rs, W1sw, W2sw);
  k_edge<<<dim3(1024), dim3(256), 0, stream>>>(
      rbf, cut, ev, idx_i, idx_j, W1sw, W2sw, b1r, b2r, b2s,
      q_ws, k_ws, alpha_ws);
  k_agg<<<dim3(6250), dim3(256), 0, stream>>>(
      alpha_ws, v_ws, ylm, idx_j, rs, out);
}